// Round 1
// baseline (769.476 us; speedup 1.0000x reference)
//
#include <hip/hip_runtime.h>
#include <math.h>

// ---------------------------------------------------------------------------
// CODA block on MI355X, fp32 throughout.
// Structure:
//   F = rfft2(inorm(x))  (one 128x65 spectrum per image, norm='forward')
//   r = irfft2_64(truncate(F))            (shared K/Q skip-resample image)
//   K,Q spatial from 32x16 mode sets + wKs*r   -> scores -> softmax
//   V/P done fully spectrally: Projdhat = A-mix(F) + mode-mix(d, attn, F)
//   projd = irfft2(Projdhat); tail (norms, M0, M1, gelu) per image.
// ---------------------------------------------------------------------------

#define EPSV 1e-5f
#define PI2 6.283185307179586f

typedef float2 cf;

__device__ __forceinline__ cf cmul(cf a, cf b){ return make_float2(a.x*b.x - a.y*b.y, a.x*b.y + a.y*b.x); }
__device__ __forceinline__ cf ldc(const float* p){ return make_float2(p[0], p[1]); }
__device__ __forceinline__ void stc(float* p, cf v){ p[0]=v.x; p[1]=v.y; }

__device__ __forceinline__ void init_tw(cf* tw, int N, float dir){
  for (int j = threadIdx.x; j < N; j += blockDim.x){
    float s, c; sincosf(dir * PI2 * (float)j / (float)N, &s, &c);
    tw[j] = make_float2(c, s);
  }
}

__device__ void breduce2(float& a, float& b){
  __shared__ float sha[8], shb[8];
  for (int off = 32; off > 0; off >>= 1){
    a += __shfl_down(a, off, 64);
    b += __shfl_down(b, off, 64);
  }
  int w = threadIdx.x >> 6, lane = threadIdx.x & 63;
  int nw = (blockDim.x + 63) >> 6;
  if (lane == 0){ sha[w] = a; shb[w] = b; }
  __syncthreads();
  if (threadIdx.x == 0){
    for (int i = 1; i < nw; ++i){ a += sha[i]; b += shb[i]; }
    sha[0] = a; shb[0] = b;
  }
  __syncthreads();
  a = sha[0]; b = shb[0];
  __syncthreads();
}

// --------------------------------------------------------------------------
__global__ __launch_bounds__(512) void k_zero(float* p, int nfl){
  int i = blockIdx.x*blockDim.x + threadIdx.x;
  if (i < nfl) p[i] = 0.f;
}

// instance-norm of x -> xa_n (per image, g=ng[0], b=nb[0])
__global__ __launch_bounds__(256) void k_inorm0(const float* __restrict__ x, const float* __restrict__ ng,
                                                const float* __restrict__ nb, float* __restrict__ out){
  int n = blockIdx.x;
  const float* im = x + n*16384;
  float s=0.f, s2=0.f;
  for (int i=threadIdx.x;i<16384;i+=256){ float v=im[i]; s+=v; s2=fmaf(v,v,s2); }
  breduce2(s,s2);
  float m = s*(1.f/16384.f), var = s2*(1.f/16384.f)-m*m;
  float A = rsqrtf(var+EPSV)*ng[0];
  float Bc = nb[0]-m*A;
  float* o = out + n*16384;
  for (int i=threadIdx.x;i<16384;i+=256) o[i] = fmaf(im[i], A, Bc);
}

// rfft along w (real->complex, kw 0..64), scaled 1/(128*128)  [forward norm]
__global__ __launch_bounds__(256) void k_rfft_row_full(const float* __restrict__ src, float* __restrict__ Cw){
  __shared__ float tile[16][128];
  __shared__ cf tw[128];
  init_tw(tw, 128, -1.f);
  int n = blockIdx.x, h0 = blockIdx.y*16;
  for (int i=threadIdx.x;i<2048;i+=256) tile[i>>7][i&127] = src[n*16384 + h0*128 + i];
  __syncthreads();
  int hl = threadIdx.x >> 4, kws = threadIdx.x & 15;
  for (int kw=kws; kw<65; kw+=16){
    float re=0.f, im=0.f; int idx=0;
    for (int w=0;w<128;++w){
      float v=tile[hl][w]; cf t=tw[idx];
      re=fmaf(v,t.x,re); im=fmaf(v,t.y,im);
      idx=(idx+kw)&127;
    }
    float* d = Cw + (((n*128)+(h0+hl))*65 + kw)*2;
    d[0]=re*(1.f/16384.f); d[1]=im*(1.f/16384.f);
  }
}

// full complex 128-point DFT along first spatial axis, 65 columns, dir=+-1
// out[n][a][kw] = sum_b in[n][b][kw] e^{dir*2pi*i*a*b/128}
__global__ __launch_bounds__(256) void k_fft_col_full(const float* __restrict__ src, float* __restrict__ dst, float dir){
  __shared__ cf col[8][128];
  __shared__ cf tw[128];
  init_tw(tw, 128, dir);
  int n = blockIdx.x, kwb = blockIdx.y*8;
  for (int i=threadIdx.x;i<1024;i+=256){
    int kwl=i>>7, h=i&127; int kw=kwb+kwl;
    col[kwl][h] = (kw<65) ? ldc(src + ((n*128+h)*65+kw)*2) : make_float2(0.f,0.f);
  }
  __syncthreads();
  int a = threadIdx.x & 127, base = threadIdx.x >> 7;
  for (int kwl=base; kwl<8; kwl+=2){
    int kw = kwb+kwl; if (kw>=65) continue;
    float re=0.f, im=0.f; int idx=0;
    for (int h=0;h<128;++h){
      cf v=col[kwl][h]; cf t=tw[idx];
      re = fmaf(v.x,t.x,re); re = fmaf(-v.y,t.y,re);
      im = fmaf(v.x,t.y,im); im = fmaf(v.y,t.x,im);
      idx=(idx+a)&127;
    }
    float* d = dst + ((n*128+a)*65+kw)*2; d[0]=re; d[1]=im;
  }
}

// r = irfft2 on 64x64 grid of truncated F (rows 0..31 & 96..127, cols 0..32)
__global__ __launch_bounds__(256) void k_rhalf(const float* __restrict__ F, float* __restrict__ r){
  __shared__ cf Fs[64][33];
  __shared__ cf As[64][33];
  __shared__ cf tw[64];
  init_tw(tw, 64, 1.f);
  int n = blockIdx.x;
  for (int i=threadIdx.x;i<2112;i+=256){
    int kh=i/33, kw=i-kh*33;
    int fr = kh<32 ? kh : kh+64;
    Fs[kh][kw] = ldc(F + ((n*128+fr)*65+kw)*2);
  }
  __syncthreads();
  for (int i=threadIdx.x;i<2112;i+=256){
    int h=i/33, kw=i-h*33;
    float re=0.f,im=0.f; int idx=0;
    for (int kh=0;kh<64;++kh){
      cf v=Fs[kh][kw]; cf t=tw[idx];
      re += v.x*t.x - v.y*t.y; im += v.x*t.y + v.y*t.x;
      idx=(idx+h)&63;
    }
    As[h][kw]=make_float2(re,im);
  }
  __syncthreads();
  for (int i=threadIdx.x;i<4096;i+=256){
    int h=i>>6, w=i&63;
    float acc=0.f; int idx=0;
    for (int kw=0;kw<33;++kw){
      cf v=As[h][kw]; cf t=tw[idx];
      float term=v.x*t.x - v.y*t.y;
      acc += (kw==0||kw==32)? term : 2.f*term;
      idx=(idx+w)&63;
    }
    r[n*4096+i]=acc;
  }
}

// K,Q spatial (64x64) per (n,o): mode-irfft (32 rows x 16 cols) + wKs*r + bKs
__global__ __launch_bounds__(256) void k_kq(const float* __restrict__ F, const float* __restrict__ r,
                     const float* __restrict__ wK, const float* __restrict__ wKs, const float* __restrict__ bKs,
                     const float* __restrict__ wQ, const float* __restrict__ wQs, const float* __restrict__ bQs,
                     float* __restrict__ Kd, float* __restrict__ Qd){
  __shared__ cf MK[32][17], MQ[32][17];
  __shared__ cf UK[64][17], UQ[64][17];
  __shared__ cf tw[64];
  init_tw(tw, 64, 1.f);
  int n = blockIdx.x, o = blockIdx.y;
  for (int i=threadIdx.x;i<512;i+=256){
    int kh32=i>>4, kw=i&15;
    int half = kh32>>4, mr = kh32&15;
    int fr = (kh32<16)? kh32 : (kh32+96);   // F rows 0..15 / 112..127
    cf Fv = ldc(F + ((n*128+fr)*65+kw)*2);
    cf wk = ldc(wK + (((half*32+o)*16+mr)*16+kw)*2);
    cf wq = ldc(wQ + (((half*32+o)*16+mr)*16+kw)*2);
    MK[kh32][kw]=cmul(wk,Fv); MQ[kh32][kw]=cmul(wq,Fv);
  }
  __syncthreads();
  for (int i=threadIdx.x;i<1024;i+=256){
    int h=i>>4, kw=i&15;
    float kr=0.f,ki=0.f,qr=0.f,qi=0.f;
    for (int kh32=0;kh32<32;++kh32){
      int kh64 = kh32 + ((kh32&16)<<1);     // 0..15, 48..63 on 64-grid
      cf t = tw[(kh64*h)&63];
      cf a = MK[kh32][kw]; kr += a.x*t.x - a.y*t.y; ki += a.x*t.y + a.y*t.x;
      cf b2= MQ[kh32][kw]; qr += b2.x*t.x - b2.y*t.y; qi += b2.x*t.y + b2.y*t.x;
    }
    UK[h][kw]=make_float2(kr,ki); UQ[h][kw]=make_float2(qr,qi);
  }
  __syncthreads();
  float sK=wKs[o], sQ=wQs[o], bK=bKs[o], bQ=bQs[o];
  float* Ko = Kd + (n*32+o)*4096;
  float* Qo = Qd + (n*32+o)*4096;
  for (int i=threadIdx.x;i<4096;i+=256){
    int h=i>>6, w=i&63;
    float ka=0.f, qa=0.f; int idx=0;
    for (int kw=0;kw<16;++kw){
      cf t = tw[idx];
      cf a = UK[h][kw]; float term = a.x*t.x - a.y*t.y; ka += kw? 2.f*term: term;
      cf b2= UQ[h][kw]; term = b2.x*t.x - b2.y*t.y;     qa += kw? 2.f*term: term;
      idx = (idx+w)&63;
    }
    float rv = r[n*4096+i];
    Ko[i] = fmaf(sK, rv, ka) + bK;
    Qo[i] = fmaf(sQ, rv, qa) + bQ;
  }
}

// scores = Q.K^T / 64, softmax over s -> attn  (one block per (b,o))
__global__ __launch_bounds__(256) void k_attn(const float* __restrict__ Qd, const float* __restrict__ Kd,
                                              float* __restrict__ attn){
  __shared__ float Qc[32][129];
  __shared__ float Kc[32][129];
  int b = blockIdx.x, o = blockIdx.y;
  float acc0=0.f,acc1=0.f,acc2=0.f,acc3=0.f;
  int t = threadIdx.x >> 3, s4 = (threadIdx.x & 7) << 2;
  for (int dc=0; dc<4096; dc+=128){
    __syncthreads();
    for (int i=threadIdx.x;i<4096;i+=256){
      int tt=i>>7, dl=i&127;
      Qc[tt][dl] = Qd[((b*32+tt)*32+o)*4096 + dc + dl];
      Kc[tt][dl] = Kd[((b*32+tt)*32+o)*4096 + dc + dl];
    }
    __syncthreads();
    for (int dl=0; dl<128; ++dl){
      float qv = Qc[t][dl];
      acc0 = fmaf(qv, Kc[s4+0][dl], acc0);
      acc1 = fmaf(qv, Kc[s4+1][dl], acc1);
      acc2 = fmaf(qv, Kc[s4+2][dl], acc2);
      acc3 = fmaf(qv, Kc[s4+3][dl], acc3);
    }
  }
  __syncthreads();
  Qc[t][s4+0]=acc0*(1.f/64.f); Qc[t][s4+1]=acc1*(1.f/64.f);
  Qc[t][s4+2]=acc2*(1.f/64.f); Qc[t][s4+3]=acc3*(1.f/64.f);
  __syncthreads();
  if (threadIdx.x < 32){
    int tt = threadIdx.x;
    float mx = -1e30f;
    for (int s=0;s<32;++s) mx = fmaxf(mx, Qc[tt][s]);
    float sum=0.f;
    for (int s=0;s<32;++s){ float e = expf(Qc[tt][s]-mx); Qc[tt][s]=e; sum+=e; }
    float inv = 1.f/sum;
    float* ap = attn + (b*32+o)*1024 + tt*32;
    for (int s=0;s<32;++s) ap[s] = Qc[tt][s]*inv;
  }
}

// A[b,t,s] = sum_o attn * wVs[o]*wPs[o]
__global__ __launch_bounds__(1024) void k_amat(const float* __restrict__ attn, const float* __restrict__ wVs,
                                               const float* __restrict__ wPs, float* __restrict__ Amat){
  int b = blockIdx.x;
  int t = threadIdx.x >> 5, s = threadIdx.x & 31;
  float a=0.f;
  for (int o=0;o<32;++o) a = fmaf(attn[(b*32+o)*1024 + t*32 + s], wVs[o]*wPs[o], a);
  Amat[b*1024 + t*32 + s] = a;
}

__device__ __forceinline__ cf wcV_col0(const float* wV, int o, int fr){
  if (fr < 16)  return ldc(wV + ((o*16+fr)*16)*2);
  if (fr >= 112) return ldc(wV + (((32+o)*16+(fr-112))*16)*2);
  return make_float2(0.f,0.f);
}

// mode part: Pm[b,t,mh,kw] = sum_o d[o,m] * sum_s attn[b,o,t,s]*F[bs,m]
// d = bP*aV_eff - wPs*wVs; aV_eff includes Hermitian symmetrization at kw==0
// (reference round-trips V through irfft2->rfft2 which projects col 0).
__global__ __launch_bounds__(256) void k_pmode(const float* __restrict__ F, const float* __restrict__ attn,
                        const float* __restrict__ wV, const float* __restrict__ wVs,
                        const float* __restrict__ wP, const float* __restrict__ wPs,
                        float* __restrict__ Pm){
  __shared__ cf Fs[32][33];
  __shared__ cf dv[32][33];
  __shared__ float att_s[32][33];
  int b = blockIdx.x, mb = blockIdx.y*32;
  for (int i=threadIdx.x;i<1024;i+=256){
    int s=i>>5, ml=i&31;
    int mm=mb+ml, mh=mm>>5, kw=mm&31;
    int fr = mh<32 ? mh : mh+64;
    Fs[s][ml] = ldc(F + (((b*32+s)*128+fr)*65+kw)*2);
  }
  for (int i=threadIdx.x;i<1024;i+=256){
    int o=i>>5, ml=i&31;
    int mm=mb+ml, mh=mm>>5, kw=mm&31;
    int fr = mh<32 ? mh : mh+64;
    int half = (mh>=32)?1:0, mr = mh&31;
    cf wp = ldc(wP + (((half*32+o)*32+mr)*32+kw)*2);
    cf bP = make_float2(wPs[o]+wp.x, wp.y);
    cf aV = make_float2(wVs[o], 0.f);
    if (kw==0){
      cf w1 = wcV_col0(wV,o,fr);
      cf w2 = wcV_col0(wV,o,(128-fr)&127);
      aV.x += 0.5f*(w1.x + w2.x);
      aV.y += 0.5f*(w1.y - w2.y);
    } else if (kw<16){
      if (fr<16){ cf wv=ldc(wV + ((o*16+fr)*16+kw)*2); aV.x+=wv.x; aV.y+=wv.y; }
      else if (fr>=112){ cf wv=ldc(wV + (((32+o)*16+(fr-112))*16+kw)*2); aV.x+=wv.x; aV.y+=wv.y; }
    }
    cf c = cmul(bP, aV);
    c.x -= wPs[o]*wVs[o];
    dv[o][ml]=c;
  }
  int ml = threadIdx.x & 31, tg = threadIdx.x >> 5;
  cf acc[4]; acc[0]=acc[1]=acc[2]=acc[3]=make_float2(0.f,0.f);
  for (int o=0;o<32;++o){
    __syncthreads();
    for (int i=threadIdx.x;i<1024;i+=256) att_s[i>>5][i&31] = attn[(b*32+o)*1024 + i];
    __syncthreads();
    cf d = dv[o][ml];
    for (int j=0;j<4;++j){
      int t = tg*4+j;
      float er=0.f,ei=0.f;
      for (int s=0;s<32;++s){
        float a=att_s[t][s]; cf Fv=Fs[s][ml];
        er=fmaf(a,Fv.x,er); ei=fmaf(a,Fv.y,ei);
      }
      acc[j].x += d.x*er - d.y*ei;
      acc[j].y += d.x*ei + d.y*er;
    }
  }
  for (int j=0;j<4;++j){
    int t = tg*4+j;
    stc(Pm + ((b*32+t)*2048 + mb+ml)*2, acc[j]);
  }
}

// Projdhat[bt,m] = sum_s A[b,t,s]*F[bs,m]  (+ Pm on P-mode set, + DC bias)
__global__ __launch_bounds__(256) void k_pdhat(const float* __restrict__ F, const float* __restrict__ Amat,
                        const float* __restrict__ Pm,
                        const float* __restrict__ wP, const float* __restrict__ wPs, const float* __restrict__ bPs,
                        const float* __restrict__ bVs, float* __restrict__ Pd){
  __shared__ float As[32][33];
  int b = blockIdx.x, tg = blockIdx.z;
  int m = blockIdx.y*256 + threadIdx.x;
  for (int i=threadIdx.x;i<1024;i+=256) As[i>>5][i&31] = Amat[b*1024+i];
  __syncthreads();
  if (m >= 8320) return;
  int kh = m/65, kw = m - kh*65;
  cf acc[8];
  #pragma unroll
  for (int j=0;j<8;++j) acc[j]=make_float2(0.f,0.f);
  for (int s=0;s<32;++s){
    cf Fv = ldc(F + ((b*32+s)*8320 + m)*2);
    #pragma unroll
    for (int j=0;j<8;++j){
      float a = As[tg*8+j][s];
      acc[j].x = fmaf(a,Fv.x,acc[j].x);
      acc[j].y = fmaf(a,Fv.y,acc[j].y);
    }
  }
  bool inP = (kw<32) && (kh<32 || kh>=96);
  int mh = (kh<32)? kh : kh-64;
  cf dc = make_float2(0.f,0.f);
  if (m==0){
    dc.x = bPs[0];
    for (int o=0;o<32;++o){
      cf wp = ldc(wP + (o*1024)*2);
      dc.x += (wPs[o]+wp.x)*bVs[o];
      dc.y += wp.y*bVs[o];
    }
  }
  for (int j=0;j<8;++j){
    int t = tg*8+j;
    cf v = acc[j];
    if (inP){ cf p = ldc(Pm + ((b*32+t)*2048 + mh*32+kw)*2); v.x+=p.x; v.y+=p.y; }
    if (m==0){ v.x+=dc.x; v.y+=dc.y; }
    stc(Pd + ((b*32+t)*8320 + m)*2, v);
  }
}

// z = irfft-row(Ag) + x ; accumulate inorm stats
__global__ __launch_bounds__(256) void k_irfft_row_addx(const float* __restrict__ Ag, const float* __restrict__ x,
                                                        float* __restrict__ z, float* __restrict__ stats){
  __shared__ cf rowA[16][66];
  __shared__ cf tw[128];
  init_tw(tw,128,1.f);
  int n=blockIdx.x, h0=blockIdx.y*16;
  for (int i=threadIdx.x;i<1040;i+=256){
    int hl=i/65, kw=i-hl*65;
    rowA[hl][kw] = ldc(Ag + ((n*128+h0+hl)*65+kw)*2);
  }
  __syncthreads();
  float s=0.f,s2=0.f;
  for (int i=threadIdx.x;i<2048;i+=256){
    int hl=i>>7, w=i&127;
    float acc=0.f; int idx=0;
    for (int kw=0;kw<65;++kw){
      cf v=rowA[hl][kw]; cf t=tw[idx];
      float term=v.x*t.x - v.y*t.y;
      acc += (kw==0||kw==64)? term : 2.f*term;
      idx=(idx+w)&127;
    }
    int gi = n*16384 + (h0+hl)*128 + w;
    acc += x[gi];
    z[gi]=acc;
    s+=acc; s2=fmaf(acc,acc,s2);
  }
  breduce2(s,s2);
  if (threadIdx.x==0){ atomicAdd(&stats[n*2],s); atomicAdd(&stats[n*2+1],s2); }
}

// M0 rfft row stage; input an computed inline from z + statsZ (double inorm)
__global__ __launch_bounds__(256) void k_rfft_row_an(const float* __restrict__ z, const float* __restrict__ statsZ,
                              const float* __restrict__ ng, const float* __restrict__ nb,
                              float* __restrict__ Tm){
  __shared__ float tile[16][128];
  __shared__ cf tw[128];
  init_tw(tw,128,-1.f);
  int n=blockIdx.x, h0=blockIdx.y*16;
  float S=statsZ[n*2], S2=statsZ[n*2+1];
  float mz=S*(1.f/16384.f), vz=S2*(1.f/16384.f)-mz*mz;
  float az=rsqrtf(vz+EPSV);
  float g1=ng[1], g2=ng[2], b2v=nb[2];
  float vat = g1*g1*vz*az*az;
  float C1 = az*g1*rsqrtf(vat+EPSV)*g2;
  float Dc = b2v - mz*C1;
  for (int i=threadIdx.x;i<2048;i+=256)
    tile[i>>7][i&127] = fmaf(z[n*16384+h0*128+i], C1, Dc);
  __syncthreads();
  for (int i=threadIdx.x;i<512;i+=256){
    int hl=i>>5, kw=i&31;
    float re=0.f,im=0.f; int idx=0;
    for (int w=0;w<128;++w){
      float v=tile[hl][w]; cf t=tw[idx];
      re=fmaf(v,t.x,re); im=fmaf(v,t.y,im);
      idx=(idx+kw)&127;
    }
    float* d = Tm + ((n*128+h0+hl)*32+kw)*2;
    d[0]=re*(1.f/16384.f); d[1]=im*(1.f/16384.f);
  }
}

// col DFT (kh on S64 rows) + spectral-weight multiply
__global__ __launch_bounds__(256) void k_mfft_col(const float* __restrict__ Tm, const float* __restrict__ wM,
                                                  float* __restrict__ Gf){
  __shared__ cf tw[128];
  init_tw(tw,128,-1.f);
  __syncthreads();
  int n = blockIdx.x;
  for (int i=threadIdx.x;i<2048;i+=256){
    int khi=i>>5, kw=i&31;
    int khF = (khi<32)? khi : khi+64;
    float re=0.f,im=0.f; int idx=0;
    for (int h=0;h<128;++h){
      cf v = ldc(Tm + ((n*128+h)*32+kw)*2);
      cf t = tw[idx];
      re += v.x*t.x - v.y*t.y; im += v.x*t.y + v.y*t.x;
      idx = (idx+khF)&127;
    }
    int half = (khi>=32)?1:0, mr = khi&31;
    cf wv = ldc(wM + ((half*32+mr)*32+kw)*2);
    stc(Gf + (n*2048 + i)*2, cmul(make_float2(re,im), wv));
  }
}

// inverse col DFT from the 64 weighted modes
__global__ __launch_bounds__(256) void k_mifft_col(const float* __restrict__ Gf, float* __restrict__ Am){
  __shared__ cf gs[64][33];
  __shared__ cf tw[128];
  init_tw(tw,128,1.f);
  int n=blockIdx.x, h0=blockIdx.y*32;
  for (int i=threadIdx.x;i<2048;i+=256) gs[i>>5][i&31] = ldc(Gf + (n*2048+i)*2);
  __syncthreads();
  for (int i=threadIdx.x;i<1024;i+=256){
    int hl=i>>5, kw=i&31; int h=h0+hl;
    float re=0.f,im=0.f;
    int idx=0;
    for (int khi=0;khi<32;++khi){
      cf v=gs[khi][kw]; cf t=tw[idx];
      re+=v.x*t.x-v.y*t.y; im+=v.x*t.y+v.y*t.x;
      idx=(idx+h)&127;
    }
    idx = (96*h)&127;
    for (int khi=32;khi<64;++khi){
      cf v=gs[khi][kw]; cf t=tw[idx];
      re+=v.x*t.x-v.y*t.y; im+=v.x*t.y+v.y*t.x;
      idx=(idx+h)&127;
    }
    stc(Am + ((n*128+h)*32+kw)*2, make_float2(re,im));
  }
}

// irfft row stage for 32-col mode spectra; writes spatial + stats
__global__ __launch_bounds__(256) void k_mirfft_row(const float* __restrict__ Am, float* __restrict__ out,
                                                    float* __restrict__ stats){
  __shared__ cf rowA[16][33];
  __shared__ cf tw[128];
  init_tw(tw,128,1.f);
  int n=blockIdx.x, h0=blockIdx.y*16;
  for (int i=threadIdx.x;i<512;i+=256){
    int hl=i>>5, kw=i&31;
    rowA[hl][kw] = ldc(Am + ((n*128+h0+hl)*32+kw)*2);
  }
  __syncthreads();
  float s=0.f,s2=0.f;
  for (int i=threadIdx.x;i<2048;i+=256){
    int hl=i>>7, w=i&127;
    float acc=0.f; int idx=0;
    for (int kw=0;kw<32;++kw){
      cf v=rowA[hl][kw]; cf t=tw[idx];
      float term=v.x*t.x-v.y*t.y;
      acc += kw? 2.f*term:term;
      idx=(idx+w)&127;
    }
    out[n*16384+(h0+hl)*128+w]=acc;
    s+=acc; s2=fmaf(acc,acc,s2);
  }
  breduce2(s,s2);
  if (threadIdx.x==0){ atomicAdd(&stats[n*2],s); atomicAdd(&stats[n*2+1],s2); }
}

// m0 = gelu(inorm(fno0)*g3+b3 + wM0s*an + bM0s); writes m0 and M1's rfft-row
__global__ __launch_bounds__(256) void k_m0_rfft_row(const float* __restrict__ fno, const float* __restrict__ z,
                              const float* __restrict__ stats0, const float* __restrict__ statsZ,
                              const float* __restrict__ ng, const float* __restrict__ nb,
                              const float* __restrict__ wM0s, const float* __restrict__ bM0s,
                              float* __restrict__ m0out, float* __restrict__ Tm){
  __shared__ float tile[16][128];
  __shared__ cf tw[128];
  init_tw(tw,128,-1.f);
  int n=blockIdx.x, h0=blockIdx.y*16;
  float S0=stats0[n*2], S02=stats0[n*2+1];
  float m0m=S0*(1.f/16384.f), v0=S02*(1.f/16384.f)-m0m*m0m;
  float A0=rsqrtf(v0+EPSV)*ng[3];
  float B0=nb[3]-m0m*A0;
  float Sz=statsZ[n*2], Sz2=statsZ[n*2+1];
  float mz=Sz*(1.f/16384.f), vz=Sz2*(1.f/16384.f)-mz*mz;
  float az=rsqrtf(vz+EPSV);
  float g1=ng[1], g2=ng[2];
  float vat=g1*g1*vz*az*az;
  float C1=az*g1*rsqrtf(vat+EPSV)*g2;
  float Dc=nb[2]-mz*C1;
  float ws_=wM0s[0], bs_=bM0s[0];
  for (int i=threadIdx.x;i<2048;i+=256){
    int gi = n*16384 + h0*128 + i;
    float nf = fmaf(fno[gi], A0, B0);
    float an = fmaf(z[gi], C1, Dc);
    float pre = nf + fmaf(ws_, an, bs_);
    float gv = 0.5f*pre*(1.f+erff(pre*0.70710678118654752f));
    tile[i>>7][i&127]=gv;
    m0out[gi]=gv;
  }
  __syncthreads();
  for (int i=threadIdx.x;i<512;i+=256){
    int hl=i>>5, kw=i&31;
    float re=0.f,im=0.f; int idx=0;
    for (int w=0;w<128;++w){
      float v=tile[hl][w]; cf t=tw[idx];
      re=fmaf(v,t.x,re); im=fmaf(v,t.y,im);
      idx=(idx+kw)&127;
    }
    float* d = Tm + ((n*128+h0+hl)*32+kw)*2;
    d[0]=re*(1.f/16384.f); d[1]=im*(1.f/16384.f);
  }
}

// m1 = inorm(fno1)*g4+b4 + wM1s*m0 + bM1s  (in-place over fno1); stats2
__global__ __launch_bounds__(256) void k_m1_mix(const float* fno1, const float* __restrict__ m0,
                         const float* __restrict__ stats1, const float* __restrict__ ng, const float* __restrict__ nb,
                         const float* __restrict__ wM1s, const float* __restrict__ bM1s,
                         float* m1out, float* __restrict__ stats2){
  int n=blockIdx.x, h0=blockIdx.y*16;
  float S=stats1[n*2], S2v=stats1[n*2+1];
  float m1m=S*(1.f/16384.f), v1=S2v*(1.f/16384.f)-m1m*m1m;
  float A1=rsqrtf(v1+EPSV)*ng[4];
  float Bc1=nb[4]-m1m*A1;
  float ws_=wM1s[0], bs_=bM1s[0];
  float s=0.f,s2=0.f;
  for (int i=threadIdx.x;i<2048;i+=256){
    int gi=n*16384+h0*128+i;
    float v = fmaf(fno1[gi],A1,Bc1) + fmaf(ws_,m0[gi],bs_);
    m1out[gi]=v;
    s+=v; s2=fmaf(v,v,s2);
  }
  breduce2(s,s2);
  if (threadIdx.x==0){ atomicAdd(&stats2[n*2],s); atomicAdd(&stats2[n*2+1],s2); }
}

// out = inorm(m1)*g5+b5 + attention, attention = (z-mz)*az*g1+b1
__global__ __launch_bounds__(256) void k_final(const float* __restrict__ m1, const float* __restrict__ z,
                        const float* __restrict__ stats2, const float* __restrict__ statsZ,
                        const float* __restrict__ ng, const float* __restrict__ nb,
                        float* __restrict__ out){
  int n=blockIdx.x, h0=blockIdx.y*16;
  float S=stats2[n*2], S2v=stats2[n*2+1];
  float mm=S*(1.f/16384.f), vv=S2v*(1.f/16384.f)-mm*mm;
  float A2=rsqrtf(vv+EPSV)*ng[5];
  float B2c=nb[5]-mm*A2;
  float Sz=statsZ[n*2], Sz2=statsZ[n*2+1];
  float mz=Sz*(1.f/16384.f), vz=Sz2*(1.f/16384.f)-mz*mz;
  float Az=rsqrtf(vz+EPSV)*ng[1];
  float Bz=nb[1]-mz*Az;
  for (int i=threadIdx.x;i<2048;i+=256){
    int gi=n*16384+h0*128+i;
    out[gi] = fmaf(m1[gi],A2,B2c) + fmaf(z[gi],Az,Bz);
  }
}

// ---------------------------------------------------------------------------
extern "C" void kernel_launch(void* const* d_in, const int* in_sizes, int n_in,
                              void* d_out, int out_size, void* d_ws, size_t ws_size,
                              hipStream_t stream){
  (void)in_sizes; (void)n_in; (void)out_size; (void)ws_size;
  const float* x   = (const float*)d_in[0];
  const float* wK  = (const float*)d_in[1];
  const float* wKs = (const float*)d_in[2];
  const float* bKs = (const float*)d_in[3];
  const float* wQ  = (const float*)d_in[4];
  const float* wQs = (const float*)d_in[5];
  const float* bQs = (const float*)d_in[6];
  const float* wV  = (const float*)d_in[7];
  const float* wVs = (const float*)d_in[8];
  const float* bVs = (const float*)d_in[9];
  const float* wP  = (const float*)d_in[10];
  const float* wPs = (const float*)d_in[11];
  const float* bPs = (const float*)d_in[12];
  const float* wM0 = (const float*)d_in[13];
  const float* wM0s= (const float*)d_in[14];
  const float* bM0s= (const float*)d_in[15];
  const float* wM1 = (const float*)d_in[16];
  const float* wM1s= (const float*)d_in[17];
  const float* bM1s= (const float*)d_in[18];
  const float* ng  = (const float*)d_in[19];
  const float* nb  = (const float*)d_in[20];
  float* out = (float*)d_out;
  float* ws  = (float*)d_ws;

  // workspace layout (floats); BIG region is reused across phases
  float* F     = ws;                    // 64*8320*2      = 1,064,960
  float* r     = F + 1064960;           // 64*4096        =   262,144
  float* attn  = r + 262144;            // 2*32*32*32     =    65,536
  float* Amat  = attn + 65536;          // 2*32*32        =     2,048
  float* Pm    = Amat + 2048;           // 2*32*2048*2    =   262,144
  float* stats = Pm + 262144;           // 4*64*2 = 512
  float* BIG   = stats + 512;           // 16,777,216 floats max
  float* xa_n  = BIG;                   // phase 1
  float* Cw    = BIG + 1048576;         // phase 1
  float* Kd    = BIG;                   // phase 2 (overwrites xa_n/Cw)
  float* Qd    = BIG + 8388608;         // phase 2
  float* Pd    = BIG;                   // phase 3 (overwrites Kd head)
  float* tail  = BIG + 1064960;         // phase 3
  float* statsZ = stats;
  float* stats0 = stats + 128;
  float* stats1 = stats + 256;
  float* stats2 = stats + 384;
  float* z   = tail;                    // 1,048,576
  float* m0b = tail + 1048576;          // 1,048,576
  float* fx  = tail + 2097152;          // 1,048,576
  float* Ag  = tail + 3145728;          // 1,064,960
  float* Tm  = tail + 4210688;          //   524,288
  float* Gf  = tail + 4734976;          //   262,144
  float* Am  = tail + 4997120;          //   524,288

  k_zero<<<1,512,0,stream>>>(stats, 512);
  k_inorm0<<<64,256,0,stream>>>(x, ng, nb, xa_n);
  k_rfft_row_full<<<dim3(64,8),256,0,stream>>>(xa_n, Cw);
  k_fft_col_full<<<dim3(64,9),256,0,stream>>>(Cw, F, -1.f);
  k_rhalf<<<64,256,0,stream>>>(F, r);
  k_kq<<<dim3(64,32),256,0,stream>>>(F, r, wK,wKs,bKs, wQ,wQs,bQs, Kd, Qd);
  k_attn<<<dim3(2,32),256,0,stream>>>(Qd, Kd, attn);
  k_amat<<<2,1024,0,stream>>>(attn, wVs, wPs, Amat);
  k_pmode<<<dim3(2,64),256,0,stream>>>(F, attn, wV, wVs, wP, wPs, Pm);
  k_pdhat<<<dim3(2,33,4),256,0,stream>>>(F, Amat, Pm, wP, wPs, bPs, bVs, Pd);
  k_fft_col_full<<<dim3(64,9),256,0,stream>>>(Pd, Ag, 1.f);
  k_irfft_row_addx<<<dim3(64,8),256,0,stream>>>(Ag, x, z, statsZ);
  k_rfft_row_an<<<dim3(64,8),256,0,stream>>>(z, statsZ, ng, nb, Tm);
  k_mfft_col<<<64,256,0,stream>>>(Tm, wM0, Gf);
  k_mifft_col<<<dim3(64,4),256,0,stream>>>(Gf, Am);
  k_mirfft_row<<<dim3(64,8),256,0,stream>>>(Am, fx, stats0);
  k_m0_rfft_row<<<dim3(64,8),256,0,stream>>>(fx, z, stats0, statsZ, ng, nb, wM0s, bM0s, m0b, Tm);
  k_mfft_col<<<64,256,0,stream>>>(Tm, wM1, Gf);
  k_mifft_col<<<dim3(64,4),256,0,stream>>>(Gf, Am);
  k_mirfft_row<<<dim3(64,8),256,0,stream>>>(Am, fx, stats1);
  k_m1_mix<<<dim3(64,8),256,0,stream>>>(fx, m0b, stats1, ng, nb, wM1s, bM1s, fx, stats2);
  k_final<<<dim3(64,8),256,0,stream>>>(fx, z, stats2, statsZ, ng, nb, out);
}

// Round 2
// 500.480 us; speedup vs baseline: 1.5375x; 1.5375x over previous
//
#include <hip/hip_runtime.h>
#include <math.h>

// ---------------------------------------------------------------------------
// CODA block on MI355X, fp32 throughout.
//   F = rfft2(inorm(x))  (one 128x65 spectrum per image, norm='forward')
//   scores computed SPECTRALLY via Parseval on the 64x64 K/Q grid:
//     scores[b,o,t,s] = 64 * sum_m Re(gamma_o[m] E_t[m] conj(E_s[m])) + DC-linear
//   V/P fully spectral: Projdhat = A-mix(F) + mode-mix(d, attn, F)
//   projd = irfft2(Projdhat); tail (norms, M0, M1, gelu) per image.
// ---------------------------------------------------------------------------

#define EPSV 1e-5f
#define PI2 6.283185307179586f

typedef float2 cf;

__device__ __forceinline__ cf cmul(cf a, cf b){ return make_float2(a.x*b.x - a.y*b.y, a.x*b.y + a.y*b.x); }
__device__ __forceinline__ cf ldc(const float* p){ return make_float2(p[0], p[1]); }
__device__ __forceinline__ void stc(float* p, cf v){ p[0]=v.x; p[1]=v.y; }

__device__ __forceinline__ void init_tw(cf* tw, int N, float dir){
  for (int j = threadIdx.x; j < N; j += blockDim.x){
    float s, c; sincosf(dir * PI2 * (float)j / (float)N, &s, &c);
    tw[j] = make_float2(c, s);
  }
}

__device__ void breduce2(float& a, float& b){
  __shared__ float sha[8], shb[8];
  for (int off = 32; off > 0; off >>= 1){
    a += __shfl_down(a, off, 64);
    b += __shfl_down(b, off, 64);
  }
  int w = threadIdx.x >> 6, lane = threadIdx.x & 63;
  int nw = (blockDim.x + 63) >> 6;
  if (lane == 0){ sha[w] = a; shb[w] = b; }
  __syncthreads();
  if (threadIdx.x == 0){
    for (int i = 1; i < nw; ++i){ a += sha[i]; b += shb[i]; }
    sha[0] = a; shb[0] = b;
  }
  __syncthreads();
  a = sha[0]; b = shb[0];
  __syncthreads();
}

// --------------------------------------------------------------------------
__global__ __launch_bounds__(512) void k_zero(float* p, int nfl){
  int i = blockIdx.x*blockDim.x + threadIdx.x;
  if (i < nfl) p[i] = 0.f;
}

// instance-norm of x -> xa_n (per image, g=ng[0], b=nb[0])
__global__ __launch_bounds__(256) void k_inorm0(const float* __restrict__ x, const float* __restrict__ ng,
                                                const float* __restrict__ nb, float* __restrict__ out){
  int n = blockIdx.x;
  const float* im = x + n*16384;
  float s=0.f, s2=0.f;
  for (int i=threadIdx.x;i<16384;i+=256){ float v=im[i]; s+=v; s2=fmaf(v,v,s2); }
  breduce2(s,s2);
  float m = s*(1.f/16384.f), var = s2*(1.f/16384.f)-m*m;
  float A = rsqrtf(var+EPSV)*ng[0];
  float Bc = nb[0]-m*A;
  float* o = out + n*16384;
  for (int i=threadIdx.x;i<16384;i+=256) o[i] = fmaf(im[i], A, Bc);
}

// rfft along w (real->complex, kw 0..64), scaled 1/(128*128)  [forward norm]
__global__ __launch_bounds__(256) void k_rfft_row_full(const float* __restrict__ src, float* __restrict__ Cw){
  __shared__ float tile[16][128];
  __shared__ cf tw[128];
  init_tw(tw, 128, -1.f);
  int n = blockIdx.x, h0 = blockIdx.y*16;
  for (int i=threadIdx.x;i<2048;i+=256) tile[i>>7][i&127] = src[n*16384 + h0*128 + i];
  __syncthreads();
  int hl = threadIdx.x >> 4, kws = threadIdx.x & 15;
  for (int kw=kws; kw<65; kw+=16){
    float re=0.f, im=0.f; int idx=0;
    for (int w=0;w<128;++w){
      float v=tile[hl][w]; cf t=tw[idx];
      re=fmaf(v,t.x,re); im=fmaf(v,t.y,im);
      idx=(idx+kw)&127;
    }
    float* d = Cw + (((n*128)+(h0+hl))*65 + kw)*2;
    d[0]=re*(1.f/16384.f); d[1]=im*(1.f/16384.f);
  }
}

// full complex 128-point DFT along first spatial axis, 65 columns, dir=+-1
__global__ __launch_bounds__(256) void k_fft_col_full(const float* __restrict__ src, float* __restrict__ dst, float dir){
  __shared__ cf col[8][128];
  __shared__ cf tw[128];
  init_tw(tw, 128, dir);
  int n = blockIdx.x, kwb = blockIdx.y*8;
  for (int i=threadIdx.x;i<1024;i+=256){
    int kwl=i>>7, h=i&127; int kw=kwb+kwl;
    col[kwl][h] = (kw<65) ? ldc(src + ((n*128+h)*65+kw)*2) : make_float2(0.f,0.f);
  }
  __syncthreads();
  int a = threadIdx.x & 127, base = threadIdx.x >> 7;
  for (int kwl=base; kwl<8; kwl+=2){
    int kw = kwb+kwl; if (kw>=65) continue;
    float re=0.f, im=0.f; int idx=0;
    for (int h=0;h<128;++h){
      cf v=col[kwl][h]; cf t=tw[idx];
      re = fmaf(v.x,t.x,re); re = fmaf(-v.y,t.y,re);
      im = fmaf(v.x,t.y,im); im = fmaf(v.y,t.x,im);
      idx=(idx+a)&127;
    }
    float* d = dst + ((n*128+a)*65+kw)*2; d[0]=re; d[1]=im;
  }
}

// ---- spectral attention-score machinery ----------------------------------
// K/Q mode weight on the 64-grid: rows 0..15 (half0) / 48..63 (half1), kw<16
__device__ __forceinline__ cf kq_mode(const float* w, int o, int kh, int kw){
  if (kw < 16){
    if (kh < 16)  return ldc(w + ((o*16+kh)*16+kw)*2);
    if (kh >= 48) return ldc(w + (((32+o)*16+(kh-48))*16+kw)*2);
  }
  return make_float2(0.f,0.f);
}

// gamma[o][m], m over 64x33 grid (m = kh*33+kw); scale 64 (Parseval) * w_kw
__global__ __launch_bounds__(256) void k_gamma(const float* __restrict__ wQ, const float* __restrict__ wQs,
                      const float* __restrict__ bQs,
                      const float* __restrict__ wK, const float* __restrict__ wKs,
                      const float* __restrict__ bKs,
                      float* __restrict__ gam, float* __restrict__ gcons){
  int o = blockIdx.x;
  float sQ=wQs[o], sK=wKs[o];
  for (int m = threadIdx.x; m < 2112; m += 256){
    int kh = m/33, kw = m-kh*33;
    cf g;
    if (kw == 0){
      int mh = (64-kh)&63;
      cf qp = kq_mode(wQ,o,kh,0);  qp.x += sQ;
      cf qm = kq_mode(wQ,o,mh,0);  qm.x += sQ;
      cf qt = make_float2(0.5f*(qp.x+qm.x), 0.5f*(qp.y-qm.y));
      cf kp = kq_mode(wK,o,kh,0);  kp.x += sK;
      cf km = kq_mode(wK,o,mh,0);  km.x += sK;
      cf kt = make_float2(0.5f*(kp.x+km.x), 0.5f*(kp.y-km.y));
      g = make_float2(64.f*(qt.x*kt.x + qt.y*kt.y), 64.f*(qt.y*kt.x - qt.x*kt.y));
    } else if (kw == 32){
      g = make_float2(64.f*sQ*sK, 0.f);
    } else {
      cf q = kq_mode(wQ,o,kh,kw); q.x += sQ;
      cf k = kq_mode(wK,o,kh,kw); k.x += sK;
      g = make_float2(128.f*(q.x*k.x + q.y*k.y), 128.f*(q.y*k.x - q.x*k.y));
    }
    stc(gam + (o*2112+m)*2, g);
  }
  if (threadIdx.x == 0){
    float qt0 = sQ + kq_mode(wQ,o,0,0).x;
    float kt0 = sK + kq_mode(wK,o,0,0).x;
    gcons[o]    = 64.f*bKs[o]*qt0;
    gcons[32+o] = 64.f*bQs[o]*kt0;
    gcons[64+o] = 64.f*bQs[o]*bKs[o];
  }
}

// E[n][m]: truncated F on 64x33 grid; col 32 Hermitian-symmetrized
__global__ __launch_bounds__(256) void k_escore(const float* __restrict__ F, float* __restrict__ Es){
  int n = blockIdx.x;
  for (int m = threadIdx.x; m < 2112; m += 256){
    int kh = m/33, kw = m-kh*33;
    int fr = kh<32 ? kh : kh+64;
    cf v;
    if (kw < 32) v = ldc(F + ((n*128+fr)*65+kw)*2);
    else {
      int mh = (64-kh)&63;
      int fr2 = mh<32 ? mh : mh+64;
      cf a = ldc(F + ((n*128+fr)*65+32)*2);
      cf b = ldc(F + ((n*128+fr2)*65+32)*2);
      v = make_float2(0.5f*(a.x+b.x), 0.5f*(a.y-b.y));
    }
    stc(Es + (n*2112+m)*2, v);
  }
}

// scores[b,o,t,s] += sum over m-slice of Re(gamma E_t conj(E_s)); split-K atomics
__global__ __launch_bounds__(256) void k_score(const float* __restrict__ Es, const float* __restrict__ gam,
                                               float* __restrict__ scores){
  __shared__ float2 Esh[88][33];   // [j][t], padded
  __shared__ float2 gsh[88];
  int b = blockIdx.x, o = blockIdx.y, mk = blockIdx.z;
  int m0 = mk*264;
  int t = threadIdx.x >> 3, s4 = (threadIdx.x & 7) << 2;
  float acc0=0.f,acc1=0.f,acc2=0.f,acc3=0.f;
  for (int ck=0; ck<3; ++ck){
    int mc = m0 + ck*88;
    __syncthreads();
    for (int i = threadIdx.x; i < 88*32; i += 256){
      int tt = i/88, j = i - tt*88;
      float2 v = *(const float2*)(Es + ((b*32+tt)*2112 + mc + j)*2);
      Esh[j][tt] = v;
    }
    for (int j = threadIdx.x; j < 88; j += 256)
      gsh[j] = *(const float2*)(gam + (o*2112 + mc + j)*2);
    __syncthreads();
    for (int j=0;j<88;++j){
      float2 g = gsh[j];
      float2 Et = Esh[j][t];
      float a  = g.x*Et.x - g.y*Et.y;
      float bb = g.x*Et.y + g.y*Et.x;
      float2 e0=Esh[j][s4], e1=Esh[j][s4+1], e2=Esh[j][s4+2], e3=Esh[j][s4+3];
      acc0 = fmaf(a,e0.x,fmaf(bb,e0.y,acc0));
      acc1 = fmaf(a,e1.x,fmaf(bb,e1.y,acc1));
      acc2 = fmaf(a,e2.x,fmaf(bb,e2.y,acc2));
      acc3 = fmaf(a,e3.x,fmaf(bb,e3.y,acc3));
    }
  }
  float* sp = scores + ((b*32+o)*32 + t)*32 + s4;
  atomicAdd(sp+0,acc0); atomicAdd(sp+1,acc1); atomicAdd(sp+2,acc2); atomicAdd(sp+3,acc3);
}

// add DC-linear bias terms, softmax over s, in place (scores buffer == attn)
__global__ __launch_bounds__(64) void k_softmax(float* __restrict__ attn, const float* __restrict__ Es,
                                                const float* __restrict__ gcons){
  int b = blockIdx.x, o = blockIdx.y;
  int t = threadIdx.x;
  if (t >= 32) return;
  float c0=gcons[o], c1=gcons[32+o], c2=gcons[64+o];
  float edt = Es[(b*32+t)*2112*2];
  float* row = attn + (b*32+o)*1024 + t*32;
  float v[32]; float mx=-1e30f;
  #pragma unroll
  for (int s=0;s<32;++s){
    float sc = row[s] + c0*edt + c1*Es[(b*32+s)*2112*2] + c2;
    v[s]=sc; mx=fmaxf(mx,sc);
  }
  float sum=0.f;
  #pragma unroll
  for (int s=0;s<32;++s){ float e=expf(v[s]-mx); v[s]=e; sum+=e; }
  float inv=1.f/sum;
  #pragma unroll
  for (int s=0;s<32;++s) row[s]=v[s]*inv;
}

// A[b,t,s] = sum_o attn * wVs[o]*wPs[o]
__global__ __launch_bounds__(1024) void k_amat(const float* __restrict__ attn, const float* __restrict__ wVs,
                                               const float* __restrict__ wPs, float* __restrict__ Amat){
  int b = blockIdx.x;
  int t = threadIdx.x >> 5, s = threadIdx.x & 31;
  float a=0.f;
  for (int o=0;o<32;++o) a = fmaf(attn[(b*32+o)*1024 + t*32 + s], wVs[o]*wPs[o], a);
  Amat[b*1024 + t*32 + s] = a;
}

__device__ __forceinline__ cf wcV_col0(const float* wV, int o, int fr){
  if (fr < 16)  return ldc(wV + ((o*16+fr)*16)*2);
  if (fr >= 112) return ldc(wV + (((32+o)*16+(fr-112))*16)*2);
  return make_float2(0.f,0.f);
}

// mode part: Pm[b,t,mh,kw] = sum_o d[o,m] * sum_s attn[b,o,t,s]*F[bs,m]
__global__ __launch_bounds__(256) void k_pmode(const float* __restrict__ F, const float* __restrict__ attn,
                        const float* __restrict__ wV, const float* __restrict__ wVs,
                        const float* __restrict__ wP, const float* __restrict__ wPs,
                        float* __restrict__ Pm){
  __shared__ cf Fs[32][33];
  __shared__ cf dv[32][33];
  __shared__ float att_s[32][33];
  int b = blockIdx.x, mb = blockIdx.y*32;
  for (int i=threadIdx.x;i<1024;i+=256){
    int s=i>>5, ml=i&31;
    int mm=mb+ml, mh=mm>>5, kw=mm&31;
    int fr = mh<32 ? mh : mh+64;
    Fs[s][ml] = ldc(F + (((b*32+s)*128+fr)*65+kw)*2);
  }
  for (int i=threadIdx.x;i<1024;i+=256){
    int o=i>>5, ml=i&31;
    int mm=mb+ml, mh=mm>>5, kw=mm&31;
    int fr = mh<32 ? mh : mh+64;
    int half = (mh>=32)?1:0, mr = mh&31;
    cf wp = ldc(wP + (((half*32+o)*32+mr)*32+kw)*2);
    cf bP = make_float2(wPs[o]+wp.x, wp.y);
    cf aV = make_float2(wVs[o], 0.f);
    if (kw==0){
      cf w1 = wcV_col0(wV,o,fr);
      cf w2 = wcV_col0(wV,o,(128-fr)&127);
      aV.x += 0.5f*(w1.x + w2.x);
      aV.y += 0.5f*(w1.y - w2.y);
    } else if (kw<16){
      if (fr<16){ cf wv=ldc(wV + ((o*16+fr)*16+kw)*2); aV.x+=wv.x; aV.y+=wv.y; }
      else if (fr>=112){ cf wv=ldc(wV + (((32+o)*16+(fr-112))*16+kw)*2); aV.x+=wv.x; aV.y+=wv.y; }
    }
    cf c = cmul(bP, aV);
    c.x -= wPs[o]*wVs[o];
    dv[o][ml]=c;
  }
  int ml = threadIdx.x & 31, tg = threadIdx.x >> 5;
  cf acc[4]; acc[0]=acc[1]=acc[2]=acc[3]=make_float2(0.f,0.f);
  for (int o=0;o<32;++o){
    __syncthreads();
    for (int i=threadIdx.x;i<1024;i+=256) att_s[i>>5][i&31] = attn[(b*32+o)*1024 + i];
    __syncthreads();
    cf d = dv[o][ml];
    for (int j=0;j<4;++j){
      int t = tg*4+j;
      float er=0.f,ei=0.f;
      for (int s=0;s<32;++s){
        float a=att_s[t][s]; cf Fv=Fs[s][ml];
        er=fmaf(a,Fv.x,er); ei=fmaf(a,Fv.y,ei);
      }
      acc[j].x += d.x*er - d.y*ei;
      acc[j].y += d.x*ei + d.y*er;
    }
  }
  for (int j=0;j<4;++j){
    int t = tg*4+j;
    stc(Pm + ((b*32+t)*2048 + mb+ml)*2, acc[j]);
  }
}

// Projdhat[bt,m] = sum_s A[b,t,s]*F[bs,m]  (+ Pm on P-mode set, + DC bias)
__global__ __launch_bounds__(256) void k_pdhat(const float* __restrict__ F, const float* __restrict__ Amat,
                        const float* __restrict__ Pm,
                        const float* __restrict__ wP, const float* __restrict__ wPs, const float* __restrict__ bPs,
                        const float* __restrict__ bVs, float* __restrict__ Pd){
  __shared__ float As[32][33];
  int b = blockIdx.x, tg = blockIdx.z;
  int m = blockIdx.y*256 + threadIdx.x;
  for (int i=threadIdx.x;i<1024;i+=256) As[i>>5][i&31] = Amat[b*1024+i];
  __syncthreads();
  if (m >= 8320) return;
  int kh = m/65, kw = m - kh*65;
  cf acc[8];
  #pragma unroll
  for (int j=0;j<8;++j) acc[j]=make_float2(0.f,0.f);
  for (int s=0;s<32;++s){
    cf Fv = ldc(F + ((b*32+s)*8320 + m)*2);
    #pragma unroll
    for (int j=0;j<8;++j){
      float a = As[tg*8+j][s];
      acc[j].x = fmaf(a,Fv.x,acc[j].x);
      acc[j].y = fmaf(a,Fv.y,acc[j].y);
    }
  }
  bool inP = (kw<32) && (kh<32 || kh>=96);
  int mh = (kh<32)? kh : kh-64;
  cf dc = make_float2(0.f,0.f);
  if (m==0){
    dc.x = bPs[0];
    for (int o=0;o<32;++o){
      cf wp = ldc(wP + (o*1024)*2);
      dc.x += (wPs[o]+wp.x)*bVs[o];
      dc.y += wp.y*bVs[o];
    }
  }
  for (int j=0;j<8;++j){
    int t = tg*8+j;
    cf v = acc[j];
    if (inP){ cf p = ldc(Pm + ((b*32+t)*2048 + mh*32+kw)*2); v.x+=p.x; v.y+=p.y; }
    if (m==0){ v.x+=dc.x; v.y+=dc.y; }
    stc(Pd + ((b*32+t)*8320 + m)*2, v);
  }
}

// z = irfft-row(Ag) + x ; accumulate inorm stats
__global__ __launch_bounds__(256) void k_irfft_row_addx(const float* __restrict__ Ag, const float* __restrict__ x,
                                                        float* __restrict__ z, float* __restrict__ stats){
  __shared__ cf rowA[16][66];
  __shared__ cf tw[128];
  init_tw(tw,128,1.f);
  int n=blockIdx.x, h0=blockIdx.y*16;
  for (int i=threadIdx.x;i<1040;i+=256){
    int hl=i/65, kw=i-hl*65;
    rowA[hl][kw] = ldc(Ag + ((n*128+h0+hl)*65+kw)*2);
  }
  __syncthreads();
  float s=0.f,s2=0.f;
  for (int i=threadIdx.x;i<2048;i+=256){
    int hl=i>>7, w=i&127;
    float acc=0.f; int idx=0;
    for (int kw=0;kw<65;++kw){
      cf v=rowA[hl][kw]; cf t=tw[idx];
      float term=v.x*t.x - v.y*t.y;
      acc += (kw==0||kw==64)? term : 2.f*term;
      idx=(idx+w)&127;
    }
    int gi = n*16384 + (h0+hl)*128 + w;
    acc += x[gi];
    z[gi]=acc;
    s+=acc; s2=fmaf(acc,acc,s2);
  }
  breduce2(s,s2);
  if (threadIdx.x==0){ atomicAdd(&stats[n*2],s); atomicAdd(&stats[n*2+1],s2); }
}

// M0 rfft row stage; input an computed inline from z + statsZ (double inorm)
__global__ __launch_bounds__(256) void k_rfft_row_an(const float* __restrict__ z, const float* __restrict__ statsZ,
                              const float* __restrict__ ng, const float* __restrict__ nb,
                              float* __restrict__ Tm){
  __shared__ float tile[16][128];
  __shared__ cf tw[128];
  init_tw(tw,128,-1.f);
  int n=blockIdx.x, h0=blockIdx.y*16;
  float S=statsZ[n*2], S2=statsZ[n*2+1];
  float mz=S*(1.f/16384.f), vz=S2*(1.f/16384.f)-mz*mz;
  float az=rsqrtf(vz+EPSV);
  float g1=ng[1], g2=ng[2], b2v=nb[2];
  float vat = g1*g1*vz*az*az;
  float C1 = az*g1*rsqrtf(vat+EPSV)*g2;
  float Dc = b2v - mz*C1;
  for (int i=threadIdx.x;i<2048;i+=256)
    tile[i>>7][i&127] = fmaf(z[n*16384+h0*128+i], C1, Dc);
  __syncthreads();
  for (int i=threadIdx.x;i<512;i+=256){
    int hl=i>>5, kw=i&31;
    float re=0.f,im=0.f; int idx=0;
    for (int w=0;w<128;++w){
      float v=tile[hl][w]; cf t=tw[idx];
      re=fmaf(v,t.x,re); im=fmaf(v,t.y,im);
      idx=(idx+kw)&127;
    }
    float* d = Tm + ((n*128+h0+hl)*32+kw)*2;
    d[0]=re*(1.f/16384.f); d[1]=im*(1.f/16384.f);
  }
}

// col DFT (kh on S64 rows) + spectral-weight multiply
__global__ __launch_bounds__(256) void k_mfft_col(const float* __restrict__ Tm, const float* __restrict__ wM,
                                                  float* __restrict__ Gf){
  __shared__ cf tw[128];
  init_tw(tw,128,-1.f);
  __syncthreads();
  int n = blockIdx.x;
  for (int i=threadIdx.x;i<2048;i+=256){
    int khi=i>>5, kw=i&31;
    int khF = (khi<32)? khi : khi+64;
    float re=0.f,im=0.f; int idx=0;
    for (int h=0;h<128;++h){
      cf v = ldc(Tm + ((n*128+h)*32+kw)*2);
      cf t = tw[idx];
      re += v.x*t.x - v.y*t.y; im += v.x*t.y + v.y*t.x;
      idx = (idx+khF)&127;
    }
    int half = (khi>=32)?1:0, mr = khi&31;
    cf wv = ldc(wM + ((half*32+mr)*32+kw)*2);
    stc(Gf + (n*2048 + i)*2, cmul(make_float2(re,im), wv));
  }
}

// inverse col DFT from the 64 weighted modes
__global__ __launch_bounds__(256) void k_mifft_col(const float* __restrict__ Gf, float* __restrict__ Am){
  __shared__ cf gs[64][33];
  __shared__ cf tw[128];
  init_tw(tw,128,1.f);
  int n=blockIdx.x, h0=blockIdx.y*32;
  for (int i=threadIdx.x;i<2048;i+=256) gs[i>>5][i&31] = ldc(Gf + (n*2048+i)*2);
  __syncthreads();
  for (int i=threadIdx.x;i<1024;i+=256){
    int hl=i>>5, kw=i&31; int h=h0+hl;
    float re=0.f,im=0.f;
    int idx=0;
    for (int khi=0;khi<32;++khi){
      cf v=gs[khi][kw]; cf t=tw[idx];
      re+=v.x*t.x-v.y*t.y; im+=v.x*t.y+v.y*t.x;
      idx=(idx+h)&127;
    }
    idx = (96*h)&127;
    for (int khi=32;khi<64;++khi){
      cf v=gs[khi][kw]; cf t=tw[idx];
      re+=v.x*t.x-v.y*t.y; im+=v.x*t.y+v.y*t.x;
      idx=(idx+h)&127;
    }
    stc(Am + ((n*128+h)*32+kw)*2, make_float2(re,im));
  }
}

// irfft row stage for 32-col mode spectra; writes spatial + stats
__global__ __launch_bounds__(256) void k_mirfft_row(const float* __restrict__ Am, float* __restrict__ out,
                                                    float* __restrict__ stats){
  __shared__ cf rowA[16][33];
  __shared__ cf tw[128];
  init_tw(tw,128,1.f);
  int n=blockIdx.x, h0=blockIdx.y*16;
  for (int i=threadIdx.x;i<512;i+=256){
    int hl=i>>5, kw=i&31;
    rowA[hl][kw] = ldc(Am + ((n*128+h0+hl)*32+kw)*2);
  }
  __syncthreads();
  float s=0.f,s2=0.f;
  for (int i=threadIdx.x;i<2048;i+=256){
    int hl=i>>7, w=i&127;
    float acc=0.f; int idx=0;
    for (int kw=0;kw<32;++kw){
      cf v=rowA[hl][kw]; cf t=tw[idx];
      float term=v.x*t.x-v.y*t.y;
      acc += kw? 2.f*term:term;
      idx=(idx+w)&127;
    }
    out[n*16384+(h0+hl)*128+w]=acc;
    s+=acc; s2=fmaf(acc,acc,s2);
  }
  breduce2(s,s2);
  if (threadIdx.x==0){ atomicAdd(&stats[n*2],s); atomicAdd(&stats[n*2+1],s2); }
}

// m0 = gelu(inorm(fno0)*g3+b3 + wM0s*an + bM0s); writes m0 and M1's rfft-row
__global__ __launch_bounds__(256) void k_m0_rfft_row(const float* __restrict__ fno, const float* __restrict__ z,
                              const float* __restrict__ stats0, const float* __restrict__ statsZ,
                              const float* __restrict__ ng, const float* __restrict__ nb,
                              const float* __restrict__ wM0s, const float* __restrict__ bM0s,
                              float* __restrict__ m0out, float* __restrict__ Tm){
  __shared__ float tile[16][128];
  __shared__ cf tw[128];
  init_tw(tw,128,-1.f);
  int n=blockIdx.x, h0=blockIdx.y*16;
  float S0=stats0[n*2], S02=stats0[n*2+1];
  float m0m=S0*(1.f/16384.f), v0=S02*(1.f/16384.f)-m0m*m0m;
  float A0=rsqrtf(v0+EPSV)*ng[3];
  float B0=nb[3]-m0m*A0;
  float Sz=statsZ[n*2], Sz2=statsZ[n*2+1];
  float mz=Sz*(1.f/16384.f), vz=Sz2*(1.f/16384.f)-mz*mz;
  float az=rsqrtf(vz+EPSV);
  float g1=ng[1], g2=ng[2];
  float vat=g1*g1*vz*az*az;
  float C1=az*g1*rsqrtf(vat+EPSV)*g2;
  float Dc=nb[2]-mz*C1;
  float ws_=wM0s[0], bs_=bM0s[0];
  for (int i=threadIdx.x;i<2048;i+=256){
    int gi = n*16384 + h0*128 + i;
    float nf = fmaf(fno[gi], A0, B0);
    float an = fmaf(z[gi], C1, Dc);
    float pre = nf + fmaf(ws_, an, bs_);
    float gv = 0.5f*pre*(1.f+erff(pre*0.70710678118654752f));
    tile[i>>7][i&127]=gv;
    m0out[gi]=gv;
  }
  __syncthreads();
  for (int i=threadIdx.x;i<512;i+=256){
    int hl=i>>5, kw=i&31;
    float re=0.f,im=0.f; int idx=0;
    for (int w=0;w<128;++w){
      float v=tile[hl][w]; cf t=tw[idx];
      re=fmaf(v,t.x,re); im=fmaf(v,t.y,im);
      idx=(idx+kw)&127;
    }
    float* d = Tm + ((n*128+h0+hl)*32+kw)*2;
    d[0]=re*(1.f/16384.f); d[1]=im*(1.f/16384.f);
  }
}

// m1 = inorm(fno1)*g4+b4 + wM1s*m0 + bM1s; stats2
__global__ __launch_bounds__(256) void k_m1_mix(const float* fno1, const float* __restrict__ m0,
                         const float* __restrict__ stats1, const float* __restrict__ ng, const float* __restrict__ nb,
                         const float* __restrict__ wM1s, const float* __restrict__ bM1s,
                         float* m1out, float* __restrict__ stats2){
  int n=blockIdx.x, h0=blockIdx.y*16;
  float S=stats1[n*2], S2v=stats1[n*2+1];
  float m1m=S*(1.f/16384.f), v1=S2v*(1.f/16384.f)-m1m*m1m;
  float A1=rsqrtf(v1+EPSV)*ng[4];
  float Bc1=nb[4]-m1m*A1;
  float ws_=wM1s[0], bs_=bM1s[0];
  float s=0.f,s2=0.f;
  for (int i=threadIdx.x;i<2048;i+=256){
    int gi=n*16384+h0*128+i;
    float v = fmaf(fno1[gi],A1,Bc1) + fmaf(ws_,m0[gi],bs_);
    m1out[gi]=v;
    s+=v; s2=fmaf(v,v,s2);
  }
  breduce2(s,s2);
  if (threadIdx.x==0){ atomicAdd(&stats2[n*2],s); atomicAdd(&stats2[n*2+1],s2); }
}

// out = inorm(m1)*g5+b5 + attention
__global__ __launch_bounds__(256) void k_final(const float* __restrict__ m1, const float* __restrict__ z,
                        const float* __restrict__ stats2, const float* __restrict__ statsZ,
                        const float* __restrict__ ng, const float* __restrict__ nb,
                        float* __restrict__ out){
  int n=blockIdx.x, h0=blockIdx.y*16;
  float S=stats2[n*2], S2v=stats2[n*2+1];
  float mm=S*(1.f/16384.f), vv=S2v*(1.f/16384.f)-mm*mm;
  float A2=rsqrtf(vv+EPSV)*ng[5];
  float B2c=nb[5]-mm*A2;
  float Sz=statsZ[n*2], Sz2=statsZ[n*2+1];
  float mz=Sz*(1.f/16384.f), vz=Sz2*(1.f/16384.f)-mz*mz;
  float Az=rsqrtf(vz+EPSV)*ng[1];
  float Bz=nb[1]-mz*Az;
  for (int i=threadIdx.x;i<2048;i+=256){
    int gi=n*16384+h0*128+i;
    out[gi] = fmaf(m1[gi],A2,B2c) + fmaf(z[gi],Az,Bz);
  }
}

// ---------------------------------------------------------------------------
extern "C" void kernel_launch(void* const* d_in, const int* in_sizes, int n_in,
                              void* d_out, int out_size, void* d_ws, size_t ws_size,
                              hipStream_t stream){
  (void)in_sizes; (void)n_in; (void)out_size; (void)ws_size;
  const float* x   = (const float*)d_in[0];
  const float* wK  = (const float*)d_in[1];
  const float* wKs = (const float*)d_in[2];
  const float* bKs = (const float*)d_in[3];
  const float* wQ  = (const float*)d_in[4];
  const float* wQs = (const float*)d_in[5];
  const float* bQs = (const float*)d_in[6];
  const float* wV  = (const float*)d_in[7];
  const float* wVs = (const float*)d_in[8];
  const float* bVs = (const float*)d_in[9];
  const float* wP  = (const float*)d_in[10];
  const float* wPs = (const float*)d_in[11];
  const float* bPs = (const float*)d_in[12];
  const float* wM0 = (const float*)d_in[13];
  const float* wM0s= (const float*)d_in[14];
  const float* bM0s= (const float*)d_in[15];
  const float* wM1 = (const float*)d_in[16];
  const float* wM1s= (const float*)d_in[17];
  const float* bM1s= (const float*)d_in[18];
  const float* ng  = (const float*)d_in[19];
  const float* nb  = (const float*)d_in[20];
  float* out = (float*)d_out;
  float* ws  = (float*)d_ws;

  // workspace layout (floats); BIG region reused across phases
  float* F     = ws;                    // 64*8320*2      = 1,064,960
  float* attn  = F + 1064960;           // scores+attn    =    65,536
  float* Amat  = attn + 65536;          //                      2,048
  float* Pm    = Amat + 2048;           //                    262,144
  float* stats = Pm + 262144;           //                        512
  float* gcons = stats + 512;           //                        128
  float* BIG   = gcons + 128;
  float* xa_n  = BIG;                   // phase 1 (dead after rfft_row)
  float* Cw    = BIG + 1048576;         // phase 1 (dead after fft_col)
  float* Es    = BIG;                   // phase 2: 64*2112*2 = 270,336
  float* gam   = BIG + 270336;          // phase 2: 32*2112*2 = 135,168
  float* Pd    = BIG;                   // phase 3 (overwrites Es/gam)
  float* tail  = BIG + 1064960;
  float* statsZ = stats;
  float* stats0 = stats + 128;
  float* stats1 = stats + 256;
  float* stats2 = stats + 384;
  float* z   = tail;                    // 1,048,576
  float* m0b = tail + 1048576;          // 1,048,576
  float* fx  = tail + 2097152;          // 1,048,576
  float* Ag  = tail + 3145728;          // 1,064,960
  float* Tm  = tail + 4210688;          //   524,288
  float* Gf  = tail + 4734976;          //   262,144
  float* Am  = tail + 4997120;          //   524,288

  // zero attn(scores accum) + Amat + Pm + stats + gcons (contiguous)
  k_zero<<<646,512,0,stream>>>(attn, 330368);
  k_inorm0<<<64,256,0,stream>>>(x, ng, nb, xa_n);
  k_rfft_row_full<<<dim3(64,8),256,0,stream>>>(xa_n, Cw);
  k_gamma<<<32,256,0,stream>>>(wQ,wQs,bQs, wK,wKs,bKs, gam, gcons);
  k_fft_col_full<<<dim3(64,9),256,0,stream>>>(Cw, F, -1.f);
  k_escore<<<64,256,0,stream>>>(F, Es);
  k_score<<<dim3(2,32,8),256,0,stream>>>(Es, gam, attn);
  k_softmax<<<dim3(2,32),64,0,stream>>>(attn, Es, gcons);
  k_amat<<<2,1024,0,stream>>>(attn, wVs, wPs, Amat);
  k_pmode<<<dim3(2,64),256,0,stream>>>(F, attn, wV, wVs, wP, wPs, Pm);
  k_pdhat<<<dim3(2,33,4),256,0,stream>>>(F, Amat, Pm, wP, wPs, bPs, bVs, Pd);
  k_fft_col_full<<<dim3(64,9),256,0,stream>>>(Pd, Ag, 1.f);
  k_irfft_row_addx<<<dim3(64,8),256,0,stream>>>(Ag, x, z, statsZ);
  k_rfft_row_an<<<dim3(64,8),256,0,stream>>>(z, statsZ, ng, nb, Tm);
  k_mfft_col<<<64,256,0,stream>>>(Tm, wM0, Gf);
  k_mifft_col<<<dim3(64,4),256,0,stream>>>(Gf, Am);
  k_mirfft_row<<<dim3(64,8),256,0,stream>>>(Am, fx, stats0);
  k_m0_rfft_row<<<dim3(64,8),256,0,stream>>>(fx, z, stats0, statsZ, ng, nb, wM0s, bM0s, m0b, Tm);
  k_mfft_col<<<64,256,0,stream>>>(Tm, wM1, Gf);
  k_mifft_col<<<dim3(64,4),256,0,stream>>>(Gf, Am);
  k_mirfft_row<<<dim3(64,8),256,0,stream>>>(Am, fx, stats1);
  k_m1_mix<<<dim3(64,8),256,0,stream>>>(fx, m0b, stats1, ng, nb, wM1s, bM1s, fx, stats2);
  k_final<<<dim3(64,8),256,0,stream>>>(fx, z, stats2, statsZ, ng, nb, out);
}

// Round 3
// 379.161 us; speedup vs baseline: 2.0294x; 1.3200x over previous
//
#include <hip/hip_runtime.h>
#include <math.h>

// ---------------------------------------------------------------------------
// CODA block on MI355X, fp32 throughout.
//   F = rfft2(inorm(x))  (one 128x65 spectrum per image, norm='forward')
//   scores computed SPECTRALLY via Parseval on the 64x64 K/Q grid
//   V/P fully spectral: Projdhat = A-mix(F) + mode-mix(d, attn, F)
//   projd = irfft2(Projdhat); tail (norms, M0, M1, gelu) per image.
// ---------------------------------------------------------------------------

#define EPSV 1e-5f
#define PI2 6.283185307179586f

typedef float2 cf;

__device__ __forceinline__ cf cmul(cf a, cf b){ return make_float2(a.x*b.x - a.y*b.y, a.x*b.y + a.y*b.x); }
__device__ __forceinline__ cf ldc(const float* p){ return make_float2(p[0], p[1]); }
__device__ __forceinline__ void stc(float* p, cf v){ p[0]=v.x; p[1]=v.y; }

__device__ __forceinline__ void init_tw(cf* tw, int N, float dir){
  for (int j = threadIdx.x; j < N; j += blockDim.x){
    float s, c; sincosf(dir * PI2 * (float)j / (float)N, &s, &c);
    tw[j] = make_float2(c, s);
  }
}

__device__ void breduce2(float& a, float& b){
  __shared__ float sha[8], shb[8];
  for (int off = 32; off > 0; off >>= 1){
    a += __shfl_down(a, off, 64);
    b += __shfl_down(b, off, 64);
  }
  int w = threadIdx.x >> 6, lane = threadIdx.x & 63;
  int nw = (blockDim.x + 63) >> 6;
  if (lane == 0){ sha[w] = a; shb[w] = b; }
  __syncthreads();
  if (threadIdx.x == 0){
    for (int i = 1; i < nw; ++i){ a += sha[i]; b += shb[i]; }
    sha[0] = a; shb[0] = b;
  }
  __syncthreads();
  a = sha[0]; b = shb[0];
  __syncthreads();
}

// --------------------------------------------------------------------------
__global__ __launch_bounds__(512) void k_zero(float* p, int nfl){
  int i = blockIdx.x*blockDim.x + threadIdx.x;
  if (i < nfl) p[i] = 0.f;
}

// instance-norm of x -> xa_n (per image, g=ng[0], b=nb[0])
__global__ __launch_bounds__(256) void k_inorm0(const float* __restrict__ x, const float* __restrict__ ng,
                                                const float* __restrict__ nb, float* __restrict__ out){
  int n = blockIdx.x;
  const float* im = x + n*16384;
  float s=0.f, s2=0.f;
  for (int i=threadIdx.x;i<16384;i+=256){ float v=im[i]; s+=v; s2=fmaf(v,v,s2); }
  breduce2(s,s2);
  float m = s*(1.f/16384.f), var = s2*(1.f/16384.f)-m*m;
  float A = rsqrtf(var+EPSV)*ng[0];
  float Bc = nb[0]-m*A;
  float* o = out + n*16384;
  for (int i=threadIdx.x;i<16384;i+=256) o[i] = fmaf(im[i], A, Bc);
}

// rfft along w (real->complex, kw 0..64), scaled 1/(128*128)  [forward norm]
__global__ __launch_bounds__(256) void k_rfft_row_full(const float* __restrict__ src, float* __restrict__ Cw){
  __shared__ float tile[16][128];
  __shared__ cf tw[128];
  init_tw(tw, 128, -1.f);
  int n = blockIdx.x, h0 = blockIdx.y*16;
  for (int i=threadIdx.x;i<2048;i+=256) tile[i>>7][i&127] = src[n*16384 + h0*128 + i];
  __syncthreads();
  int hl = threadIdx.x >> 4, kws = threadIdx.x & 15;
  for (int kw=kws; kw<65; kw+=16){
    float re=0.f, im=0.f; int idx=0;
    for (int w=0;w<128;++w){
      float v=tile[hl][w]; cf t=tw[idx];
      re=fmaf(v,t.x,re); im=fmaf(v,t.y,im);
      idx=(idx+kw)&127;
    }
    float* d = Cw + (((n*128)+(h0+hl))*65 + kw)*2;
    d[0]=re*(1.f/16384.f); d[1]=im*(1.f/16384.f);
  }
}

// full complex 128-point DFT along first spatial axis, 65 columns, dir=+-1
// grid (64, 17): 4-wide kw tiles
__global__ __launch_bounds__(256) void k_fft_col_full(const float* __restrict__ src, float* __restrict__ dst, float dir){
  __shared__ cf col[4][128];
  __shared__ cf tw[128];
  init_tw(tw, 128, dir);
  int n = blockIdx.x, kwb = blockIdx.y*4;
  for (int i=threadIdx.x;i<512;i+=256){
    int kwl=i>>7, h=i&127; int kw=kwb+kwl;
    col[kwl][h] = (kw<65) ? ldc(src + ((n*128+h)*65+kw)*2) : make_float2(0.f,0.f);
  }
  __syncthreads();
  int a = threadIdx.x & 127, base = threadIdx.x >> 7;
  for (int kwl=base; kwl<4; kwl+=2){
    int kw = kwb+kwl; if (kw>=65) continue;
    float re=0.f, im=0.f; int idx=0;
    for (int h=0;h<128;++h){
      cf v=col[kwl][h]; cf t=tw[idx];
      re = fmaf(v.x,t.x,re); re = fmaf(-v.y,t.y,re);
      im = fmaf(v.x,t.y,im); im = fmaf(v.y,t.x,im);
      idx=(idx+a)&127;
    }
    float* d = dst + ((n*128+a)*65+kw)*2; d[0]=re; d[1]=im;
  }
}

// ---- spectral attention-score machinery ----------------------------------
__device__ __forceinline__ cf kq_mode(const float* w, int o, int kh, int kw){
  if (kw < 16){
    if (kh < 16)  return ldc(w + ((o*16+kh)*16+kw)*2);
    if (kh >= 48) return ldc(w + (((32+o)*16+(kh-48))*16+kw)*2);
  }
  return make_float2(0.f,0.f);
}

// gamma[o][m], m over 64x33 grid (m = kh*33+kw); scale 64 (Parseval) * w_kw
__global__ __launch_bounds__(256) void k_gamma(const float* __restrict__ wQ, const float* __restrict__ wQs,
                      const float* __restrict__ bQs,
                      const float* __restrict__ wK, const float* __restrict__ wKs,
                      const float* __restrict__ bKs,
                      float* __restrict__ gam, float* __restrict__ gcons){
  int o = blockIdx.x;
  float sQ=wQs[o], sK=wKs[o];
  for (int m = threadIdx.x; m < 2112; m += 256){
    int kh = m/33, kw = m-kh*33;
    cf g;
    if (kw == 0){
      int mh = (64-kh)&63;
      cf qp = kq_mode(wQ,o,kh,0);  qp.x += sQ;
      cf qm = kq_mode(wQ,o,mh,0);  qm.x += sQ;
      cf qt = make_float2(0.5f*(qp.x+qm.x), 0.5f*(qp.y-qm.y));
      cf kp = kq_mode(wK,o,kh,0);  kp.x += sK;
      cf km = kq_mode(wK,o,mh,0);  km.x += sK;
      cf kt = make_float2(0.5f*(kp.x+km.x), 0.5f*(kp.y-km.y));
      g = make_float2(64.f*(qt.x*kt.x + qt.y*kt.y), 64.f*(qt.y*kt.x - qt.x*kt.y));
    } else if (kw == 32){
      g = make_float2(64.f*sQ*sK, 0.f);
    } else {
      cf q = kq_mode(wQ,o,kh,kw); q.x += sQ;
      cf k = kq_mode(wK,o,kh,kw); k.x += sK;
      g = make_float2(128.f*(q.x*k.x + q.y*k.y), 128.f*(q.y*k.x - q.x*k.y));
    }
    stc(gam + (o*2112+m)*2, g);
  }
  if (threadIdx.x == 0){
    float qt0 = sQ + kq_mode(wQ,o,0,0).x;
    float kt0 = sK + kq_mode(wK,o,0,0).x;
    gcons[o]    = 64.f*bKs[o]*qt0;
    gcons[32+o] = 64.f*bQs[o]*kt0;
    gcons[64+o] = 64.f*bQs[o]*bKs[o];
  }
}

// E[n][m]: truncated F on 64x33 grid; col 32 Hermitian-symmetrized
__global__ __launch_bounds__(256) void k_escore(const float* __restrict__ F, float* __restrict__ Es){
  int n = blockIdx.x;
  for (int m = threadIdx.x; m < 2112; m += 256){
    int kh = m/33, kw = m-kh*33;
    int fr = kh<32 ? kh : kh+64;
    cf v;
    if (kw < 32) v = ldc(F + ((n*128+fr)*65+kw)*2);
    else {
      int mh = (64-kh)&63;
      int fr2 = mh<32 ? mh : mh+64;
      cf a = ldc(F + ((n*128+fr)*65+32)*2);
      cf b = ldc(F + ((n*128+fr2)*65+32)*2);
      v = make_float2(0.5f*(a.x+b.x), 0.5f*(a.y-b.y));
    }
    stc(Es + (n*2112+m)*2, v);
  }
}

// scores[b,o,t,s] += sum over m-slice of Re(gamma E_t conj(E_s)); split-K atomics
__global__ __launch_bounds__(256) void k_score(const float* __restrict__ Es, const float* __restrict__ gam,
                                               float* __restrict__ scores){
  __shared__ float2 Esh[88][33];
  __shared__ float2 gsh[88];
  int b = blockIdx.x, o = blockIdx.y, mk = blockIdx.z;
  int m0 = mk*264;
  int t = threadIdx.x >> 3, s4 = (threadIdx.x & 7) << 2;
  float acc0=0.f,acc1=0.f,acc2=0.f,acc3=0.f;
  for (int ck=0; ck<3; ++ck){
    int mc = m0 + ck*88;
    __syncthreads();
    for (int i = threadIdx.x; i < 88*32; i += 256){
      int tt = i/88, j = i - tt*88;
      float2 v = *(const float2*)(Es + ((b*32+tt)*2112 + mc + j)*2);
      Esh[j][tt] = v;
    }
    for (int j = threadIdx.x; j < 88; j += 256)
      gsh[j] = *(const float2*)(gam + (o*2112 + mc + j)*2);
    __syncthreads();
    for (int j=0;j<88;++j){
      float2 g = gsh[j];
      float2 Et = Esh[j][t];
      float a  = g.x*Et.x - g.y*Et.y;
      float bb = g.x*Et.y + g.y*Et.x;
      float2 e0=Esh[j][s4], e1=Esh[j][s4+1], e2=Esh[j][s4+2], e3=Esh[j][s4+3];
      acc0 = fmaf(a,e0.x,fmaf(bb,e0.y,acc0));
      acc1 = fmaf(a,e1.x,fmaf(bb,e1.y,acc1));
      acc2 = fmaf(a,e2.x,fmaf(bb,e2.y,acc2));
      acc3 = fmaf(a,e3.x,fmaf(bb,e3.y,acc3));
    }
  }
  float* sp = scores + ((b*32+o)*32 + t)*32 + s4;
  atomicAdd(sp+0,acc0); atomicAdd(sp+1,acc1); atomicAdd(sp+2,acc2); atomicAdd(sp+3,acc3);
}

// add DC-linear bias terms, softmax over s, in place
__global__ __launch_bounds__(64) void k_softmax(float* __restrict__ attn, const float* __restrict__ Es,
                                                const float* __restrict__ gcons){
  int b = blockIdx.x, o = blockIdx.y;
  int t = threadIdx.x;
  if (t >= 32) return;
  float c0=gcons[o], c1=gcons[32+o], c2=gcons[64+o];
  float edt = Es[(b*32+t)*2112*2];
  float* row = attn + (b*32+o)*1024 + t*32;
  float v[32]; float mx=-1e30f;
  #pragma unroll
  for (int s=0;s<32;++s){
    float sc = row[s] + c0*edt + c1*Es[(b*32+s)*2112*2] + c2;
    v[s]=sc; mx=fmaxf(mx,sc);
  }
  float sum=0.f;
  #pragma unroll
  for (int s=0;s<32;++s){ float e=expf(v[s]-mx); v[s]=e; sum+=e; }
  float inv=1.f/sum;
  #pragma unroll
  for (int s=0;s<32;++s) row[s]=v[s]*inv;
}

// A[b,t,s] = sum_o attn * wVs[o]*wPs[o]
__global__ __launch_bounds__(1024) void k_amat(const float* __restrict__ attn, const float* __restrict__ wVs,
                                               const float* __restrict__ wPs, float* __restrict__ Amat){
  int b = blockIdx.x;
  int t = threadIdx.x >> 5, s = threadIdx.x & 31;
  float a=0.f;
  for (int o=0;o<32;++o) a = fmaf(attn[(b*32+o)*1024 + t*32 + s], wVs[o]*wPs[o], a);
  Amat[b*1024 + t*32 + s] = a;
}

__device__ __forceinline__ cf wcV_col0(const float* wV, int o, int fr){
  if (fr < 16)  return ldc(wV + ((o*16+fr)*16)*2);
  if (fr >= 112) return ldc(wV + (((32+o)*16+(fr-112))*16)*2);
  return make_float2(0.f,0.f);
}

// mode part: Pm[b,t,mh,kw] = sum_o d[o,m] * sum_s attn[b,o,t,s]*F[bs,m]
// grid (2, 64 mh, 4 tg); 256 thr = 8 tl x 32 kw; barrier-free main loop.
__global__ __launch_bounds__(256) void k_pmode(const float* __restrict__ F, const float* __restrict__ attn,
                        const float* __restrict__ wV, const float* __restrict__ wVs,
                        const float* __restrict__ wP, const float* __restrict__ wPs,
                        float* __restrict__ Pm){
  __shared__ float att[32][8][32];   // [o][tl][s]
  __shared__ cf Fsh[32][32];         // [s][kw]
  __shared__ cf dsh[32][32];         // [o][kw]
  int b = blockIdx.x, mh = blockIdx.y, tg = blockIdx.z;
  int fr = mh<32 ? mh : mh+64;
  int half = (mh>=32)?1:0, mr = mh&31;
  for (int i=threadIdx.x; i<8192; i+=256){
    int o = i>>8, r = i&255;
    att[o][r>>5][r&31] = attn[(b*32+o)*1024 + tg*256 + r];
  }
  for (int i=threadIdx.x; i<1024; i+=256){
    int s=i>>5, kw=i&31;
    Fsh[s][kw] = ldc(F + (((b*32+s)*128+fr)*65+kw)*2);
  }
  for (int i=threadIdx.x; i<1024; i+=256){
    int o=i>>5, kw=i&31;
    cf wp = ldc(wP + (((half*32+o)*32+mr)*32+kw)*2);
    cf bP = make_float2(wPs[o]+wp.x, wp.y);
    cf aV = make_float2(wVs[o], 0.f);
    if (kw==0){
      cf w1 = wcV_col0(wV,o,fr);
      cf w2 = wcV_col0(wV,o,(128-fr)&127);
      aV.x += 0.5f*(w1.x + w2.x);
      aV.y += 0.5f*(w1.y - w2.y);
    } else if (kw<16){
      if (fr<16){ cf wv=ldc(wV + ((o*16+fr)*16+kw)*2); aV.x+=wv.x; aV.y+=wv.y; }
      else if (fr>=112){ cf wv=ldc(wV + (((32+o)*16+(fr-112))*16+kw)*2); aV.x+=wv.x; aV.y+=wv.y; }
    }
    cf c = cmul(bP, aV);
    c.x -= wPs[o]*wVs[o];
    dsh[o][kw]=c;
  }
  __syncthreads();
  int tl = threadIdx.x>>5, kw = threadIdx.x&31;
  float ax=0.f, ay=0.f;
  for (int o=0;o<32;++o){
    float er=0.f, ei=0.f;
    #pragma unroll
    for (int s4=0;s4<32;s4+=4){
      float4 a4 = *(const float4*)&att[o][tl][s4];
      cf f0=Fsh[s4][kw], f1=Fsh[s4+1][kw], f2=Fsh[s4+2][kw], f3=Fsh[s4+3][kw];
      er=fmaf(a4.x,f0.x,er); ei=fmaf(a4.x,f0.y,ei);
      er=fmaf(a4.y,f1.x,er); ei=fmaf(a4.y,f1.y,ei);
      er=fmaf(a4.z,f2.x,er); ei=fmaf(a4.z,f2.y,ei);
      er=fmaf(a4.w,f3.x,er); ei=fmaf(a4.w,f3.y,ei);
    }
    cf d = dsh[o][kw];
    ax += d.x*er - d.y*ei;
    ay += d.x*ei + d.y*er;
  }
  int t = tg*8+tl;
  stc(Pm + ((b*32+t)*2048 + mh*32+kw)*2, make_float2(ax,ay));
}

// Projdhat[bt,m] = sum_s A[b,t,s]*F[bs,m]  (+ Pm on P-mode set, + DC bias)
__global__ __launch_bounds__(256) void k_pdhat(const float* __restrict__ F, const float* __restrict__ Amat,
                        const float* __restrict__ Pm,
                        const float* __restrict__ wP, const float* __restrict__ wPs, const float* __restrict__ bPs,
                        const float* __restrict__ bVs, float* __restrict__ Pd){
  __shared__ float As[32][33];
  int b = blockIdx.x, tg = blockIdx.z;
  int m = blockIdx.y*256 + threadIdx.x;
  for (int i=threadIdx.x;i<1024;i+=256) As[i>>5][i&31] = Amat[b*1024+i];
  __syncthreads();
  if (m >= 8320) return;
  int kh = m/65, kw = m - kh*65;
  cf acc[8];
  #pragma unroll
  for (int j=0;j<8;++j) acc[j]=make_float2(0.f,0.f);
  for (int s=0;s<32;++s){
    cf Fv = ldc(F + ((b*32+s)*8320 + m)*2);
    #pragma unroll
    for (int j=0;j<8;++j){
      float a = As[tg*8+j][s];
      acc[j].x = fmaf(a,Fv.x,acc[j].x);
      acc[j].y = fmaf(a,Fv.y,acc[j].y);
    }
  }
  bool inP = (kw<32) && (kh<32 || kh>=96);
  int mh = (kh<32)? kh : kh-64;
  cf dc = make_float2(0.f,0.f);
  if (m==0){
    dc.x = bPs[0];
    for (int o=0;o<32;++o){
      cf wp = ldc(wP + (o*1024)*2);
      dc.x += (wPs[o]+wp.x)*bVs[o];
      dc.y += wp.y*bVs[o];
    }
  }
  for (int j=0;j<8;++j){
    int t = tg*8+j;
    cf v = acc[j];
    if (inP){ cf p = ldc(Pm + ((b*32+t)*2048 + mh*32+kw)*2); v.x+=p.x; v.y+=p.y; }
    if (m==0){ v.x+=dc.x; v.y+=dc.y; }
    stc(Pd + ((b*32+t)*8320 + m)*2, v);
  }
}

// z = irfft-row(Ag) + x ; accumulate inorm stats
__global__ __launch_bounds__(256) void k_irfft_row_addx(const float* __restrict__ Ag, const float* __restrict__ x,
                                                        float* __restrict__ z, float* __restrict__ stats){
  __shared__ cf rowA[16][66];
  __shared__ cf tw[128];
  init_tw(tw,128,1.f);
  int n=blockIdx.x, h0=blockIdx.y*16;
  for (int i=threadIdx.x;i<1040;i+=256){
    int hl=i/65, kw=i-hl*65;
    rowA[hl][kw] = ldc(Ag + ((n*128+h0+hl)*65+kw)*2);
  }
  __syncthreads();
  float s=0.f,s2=0.f;
  for (int i=threadIdx.x;i<2048;i+=256){
    int hl=i>>7, w=i&127;
    float acc=0.f; int idx=0;
    for (int kw=0;kw<65;++kw){
      cf v=rowA[hl][kw]; cf t=tw[idx];
      float term=v.x*t.x - v.y*t.y;
      acc += (kw==0||kw==64)? term : 2.f*term;
      idx=(idx+w)&127;
    }
    int gi = n*16384 + (h0+hl)*128 + w;
    acc += x[gi];
    z[gi]=acc;
    s+=acc; s2=fmaf(acc,acc,s2);
  }
  breduce2(s,s2);
  if (threadIdx.x==0){ atomicAdd(&stats[n*2],s); atomicAdd(&stats[n*2+1],s2); }
}

// M0 rfft row stage; input an computed inline from z + statsZ (double inorm)
__global__ __launch_bounds__(256) void k_rfft_row_an(const float* __restrict__ z, const float* __restrict__ statsZ,
                              const float* __restrict__ ng, const float* __restrict__ nb,
                              float* __restrict__ Tm){
  __shared__ float tile[16][128];
  __shared__ cf tw[128];
  init_tw(tw,128,-1.f);
  int n=blockIdx.x, h0=blockIdx.y*16;
  float S=statsZ[n*2], S2=statsZ[n*2+1];
  float mz=S*(1.f/16384.f), vz=S2*(1.f/16384.f)-mz*mz;
  float az=rsqrtf(vz+EPSV);
  float g1=ng[1], g2=ng[2], b2v=nb[2];
  float vat = g1*g1*vz*az*az;
  float C1 = az*g1*rsqrtf(vat+EPSV)*g2;
  float Dc = b2v - mz*C1;
  for (int i=threadIdx.x;i<2048;i+=256)
    tile[i>>7][i&127] = fmaf(z[n*16384+h0*128+i], C1, Dc);
  __syncthreads();
  for (int i=threadIdx.x;i<512;i+=256){
    int hl=i>>5, kw=i&31;
    float re=0.f,im=0.f; int idx=0;
    for (int w=0;w<128;++w){
      float v=tile[hl][w]; cf t=tw[idx];
      re=fmaf(v,t.x,re); im=fmaf(v,t.y,im);
      idx=(idx+kw)&127;
    }
    float* d = Tm + ((n*128+h0+hl)*32+kw)*2;
    d[0]=re*(1.f/16384.f); d[1]=im*(1.f/16384.f);
  }
}

// col DFT (kh on S64 rows) + spectral-weight multiply; grid (64, 8)
__global__ __launch_bounds__(256) void k_mfft_col(const float* __restrict__ Tm, const float* __restrict__ wM,
                                                  float* __restrict__ Gf){
  __shared__ cf Tsh[128][32];
  __shared__ cf tw[128];
  init_tw(tw,128,-1.f);
  int n = blockIdx.x;
  for (int i=threadIdx.x;i<4096;i+=256)
    Tsh[i>>5][i&31] = ldc(Tm + (n*4096 + i)*2);
  __syncthreads();
  int khl = threadIdx.x>>5, kw = threadIdx.x&31;
  int khi = blockIdx.y*8 + khl;
  int khF = (khi<32)? khi : khi+64;
  float re=0.f, im=0.f; int idx=0;
  for (int h=0;h<128;++h){
    cf v=Tsh[h][kw]; cf t=tw[idx];
    re += v.x*t.x - v.y*t.y; im += v.x*t.y + v.y*t.x;
    idx=(idx+khF)&127;
  }
  int half=(khi>=32)?1:0, mr=khi&31;
  cf wv = ldc(wM + ((half*32+mr)*32+kw)*2);
  stc(Gf + (n*2048 + khi*32 + kw)*2, cmul(make_float2(re,im), wv));
}

// inverse col DFT from the 64 weighted modes; grid (64, 8)
__global__ __launch_bounds__(256) void k_mifft_col(const float* __restrict__ Gf, float* __restrict__ Am){
  __shared__ cf gs[64][33];
  __shared__ cf tw[128];
  init_tw(tw,128,1.f);
  int n=blockIdx.x, h0=blockIdx.y*16;
  for (int i=threadIdx.x;i<2048;i+=256) gs[i>>5][i&31] = ldc(Gf + (n*2048+i)*2);
  __syncthreads();
  for (int i=threadIdx.x;i<512;i+=256){
    int hl=i>>5, kw=i&31; int h=h0+hl;
    float re=0.f,im=0.f;
    int idx=0;
    for (int khi=0;khi<32;++khi){
      cf v=gs[khi][kw]; cf t=tw[idx];
      re+=v.x*t.x-v.y*t.y; im+=v.x*t.y+v.y*t.x;
      idx=(idx+h)&127;
    }
    idx = (96*h)&127;
    for (int khi=32;khi<64;++khi){
      cf v=gs[khi][kw]; cf t=tw[idx];
      re+=v.x*t.x-v.y*t.y; im+=v.x*t.y+v.y*t.x;
      idx=(idx+h)&127;
    }
    stc(Am + ((n*128+h)*32+kw)*2, make_float2(re,im));
  }
}

// irfft row stage for 32-col mode spectra; writes spatial + stats
__global__ __launch_bounds__(256) void k_mirfft_row(const float* __restrict__ Am, float* __restrict__ out,
                                                    float* __restrict__ stats){
  __shared__ cf rowA[16][33];
  __shared__ cf tw[128];
  init_tw(tw,128,1.f);
  int n=blockIdx.x, h0=blockIdx.y*16;
  for (int i=threadIdx.x;i<512;i+=256){
    int hl=i>>5, kw=i&31;
    rowA[hl][kw] = ldc(Am + ((n*128+h0+hl)*32+kw)*2);
  }
  __syncthreads();
  float s=0.f,s2=0.f;
  for (int i=threadIdx.x;i<2048;i+=256){
    int hl=i>>7, w=i&127;
    float acc=0.f; int idx=0;
    for (int kw=0;kw<32;++kw){
      cf v=rowA[hl][kw]; cf t=tw[idx];
      float term=v.x*t.x-v.y*t.y;
      acc += kw? 2.f*term:term;
      idx=(idx+w)&127;
    }
    out[n*16384+(h0+hl)*128+w]=acc;
    s+=acc; s2=fmaf(acc,acc,s2);
  }
  breduce2(s,s2);
  if (threadIdx.x==0){ atomicAdd(&stats[n*2],s); atomicAdd(&stats[n*2+1],s2); }
}

// m0 = gelu(inorm(fno0)*g3+b3 + wM0s*an + bM0s); writes m0 and M1's rfft-row
__global__ __launch_bounds__(256) void k_m0_rfft_row(const float* __restrict__ fno, const float* __restrict__ z,
                              const float* __restrict__ stats0, const float* __restrict__ statsZ,
                              const float* __restrict__ ng, const float* __restrict__ nb,
                              const float* __restrict__ wM0s, const float* __restrict__ bM0s,
                              float* __restrict__ m0out, float* __restrict__ Tm){
  __shared__ float tile[16][128];
  __shared__ cf tw[128];
  init_tw(tw,128,-1.f);
  int n=blockIdx.x, h0=blockIdx.y*16;
  float S0=stats0[n*2], S02=stats0[n*2+1];
  float m0m=S0*(1.f/16384.f), v0=S02*(1.f/16384.f)-m0m*m0m;
  float A0=rsqrtf(v0+EPSV)*ng[3];
  float B0=nb[3]-m0m*A0;
  float Sz=statsZ[n*2], Sz2=statsZ[n*2+1];
  float mz=Sz*(1.f/16384.f), vz=Sz2*(1.f/16384.f)-mz*mz;
  float az=rsqrtf(vz+EPSV);
  float g1=ng[1], g2=ng[2];
  float vat=g1*g1*vz*az*az;
  float C1=az*g1*rsqrtf(vat+EPSV)*g2;
  float Dc=nb[2]-mz*C1;
  float ws_=wM0s[0], bs_=bM0s[0];
  for (int i=threadIdx.x;i<2048;i+=256){
    int gi = n*16384 + h0*128 + i;
    float nf = fmaf(fno[gi], A0, B0);
    float an = fmaf(z[gi], C1, Dc);
    float pre = nf + fmaf(ws_, an, bs_);
    float gv = 0.5f*pre*(1.f+erff(pre*0.70710678118654752f));
    tile[i>>7][i&127]=gv;
    m0out[gi]=gv;
  }
  __syncthreads();
  for (int i=threadIdx.x;i<512;i+=256){
    int hl=i>>5, kw=i&31;
    float re=0.f,im=0.f; int idx=0;
    for (int w=0;w<128;++w){
      float v=tile[hl][w]; cf t=tw[idx];
      re=fmaf(v,t.x,re); im=fmaf(v,t.y,im);
      idx=(idx+kw)&127;
    }
    float* d = Tm + ((n*128+h0+hl)*32+kw)*2;
    d[0]=re*(1.f/16384.f); d[1]=im*(1.f/16384.f);
  }
}

// m1 = inorm(fno1)*g4+b4 + wM1s*m0 + bM1s; stats2
__global__ __launch_bounds__(256) void k_m1_mix(const float* fno1, const float* __restrict__ m0,
                         const float* __restrict__ stats1, const float* __restrict__ ng, const float* __restrict__ nb,
                         const float* __restrict__ wM1s, const float* __restrict__ bM1s,
                         float* m1out, float* __restrict__ stats2){
  int n=blockIdx.x, h0=blockIdx.y*16;
  float S=stats1[n*2], S2v=stats1[n*2+1];
  float m1m=S*(1.f/16384.f), v1=S2v*(1.f/16384.f)-m1m*m1m;
  float A1=rsqrtf(v1+EPSV)*ng[4];
  float Bc1=nb[4]-m1m*A1;
  float ws_=wM1s[0], bs_=bM1s[0];
  float s=0.f,s2=0.f;
  for (int i=threadIdx.x;i<2048;i+=256){
    int gi=n*16384+h0*128+i;
    float v = fmaf(fno1[gi],A1,Bc1) + fmaf(ws_,m0[gi],bs_);
    m1out[gi]=v;
    s+=v; s2=fmaf(v,v,s2);
  }
  breduce2(s,s2);
  if (threadIdx.x==0){ atomicAdd(&stats2[n*2],s); atomicAdd(&stats2[n*2+1],s2); }
}

// out = inorm(m1)*g5+b5 + attention
__global__ __launch_bounds__(256) void k_final(const float* __restrict__ m1, const float* __restrict__ z,
                        const float* __restrict__ stats2, const float* __restrict__ statsZ,
                        const float* __restrict__ ng, const float* __restrict__ nb,
                        float* __restrict__ out){
  int n=blockIdx.x, h0=blockIdx.y*16;
  float S=stats2[n*2], S2v=stats2[n*2+1];
  float mm=S*(1.f/16384.f), vv=S2v*(1.f/16384.f)-mm*mm;
  float A2=rsqrtf(vv+EPSV)*ng[5];
  float B2c=nb[5]-mm*A2;
  float Sz=statsZ[n*2], Sz2=statsZ[n*2+1];
  float mz=Sz*(1.f/16384.f), vz=Sz2*(1.f/16384.f)-mz*mz;
  float Az=rsqrtf(vz+EPSV)*ng[1];
  float Bz=nb[1]-mz*Az;
  for (int i=threadIdx.x;i<2048;i+=256){
    int gi=n*16384+h0*128+i;
    out[gi] = fmaf(m1[gi],A2,B2c) + fmaf(z[gi],Az,Bz);
  }
}

// ---------------------------------------------------------------------------
extern "C" void kernel_launch(void* const* d_in, const int* in_sizes, int n_in,
                              void* d_out, int out_size, void* d_ws, size_t ws_size,
                              hipStream_t stream){
  (void)in_sizes; (void)n_in; (void)out_size; (void)ws_size;
  const float* x   = (const float*)d_in[0];
  const float* wK  = (const float*)d_in[1];
  const float* wKs = (const float*)d_in[2];
  const float* bKs = (const float*)d_in[3];
  const float* wQ  = (const float*)d_in[4];
  const float* wQs = (const float*)d_in[5];
  const float* bQs = (const float*)d_in[6];
  const float* wV  = (const float*)d_in[7];
  const float* wVs = (const float*)d_in[8];
  const float* bVs = (const float*)d_in[9];
  const float* wP  = (const float*)d_in[10];
  const float* wPs = (const float*)d_in[11];
  const float* bPs = (const float*)d_in[12];
  const float* wM0 = (const float*)d_in[13];
  const float* wM0s= (const float*)d_in[14];
  const float* bM0s= (const float*)d_in[15];
  const float* wM1 = (const float*)d_in[16];
  const float* wM1s= (const float*)d_in[17];
  const float* bM1s= (const float*)d_in[18];
  const float* ng  = (const float*)d_in[19];
  const float* nb  = (const float*)d_in[20];
  float* out = (float*)d_out;
  float* ws  = (float*)d_ws;

  // workspace layout (floats); zero region [attn, stats] contiguous
  float* F     = ws;                    // 1,064,960
  float* attn  = F + 1064960;           //    65,536  (needs zero: atomics)
  float* stats = attn + 65536;          //       512  (needs zero: atomics)
  float* Amat  = stats + 512;           //     2,048
  float* Pm    = Amat + 2048;           //   262,144
  float* gcons = Pm + 262144;           //       128
  float* BIG   = gcons + 128;
  float* xa_n  = BIG;                   // phase 1
  float* Cw    = BIG + 1048576;         // phase 1
  float* Es    = BIG;                   // phase 2: 270,336
  float* gam   = BIG + 270336;          // phase 2: 135,168
  float* Pd    = BIG;                   // phase 3
  float* tail  = BIG + 1064960;
  float* statsZ = stats;
  float* stats0 = stats + 128;
  float* stats1 = stats + 256;
  float* stats2 = stats + 384;
  float* z   = tail;                    // 1,048,576
  float* m0b = tail + 1048576;          // 1,048,576
  float* fx  = tail + 2097152;          // 1,048,576
  float* Ag  = tail + 3145728;          // 1,064,960
  float* Tm  = tail + 4210688;          //   524,288
  float* Gf  = tail + 4734976;          //   262,144
  float* Am  = tail + 4997120;          //   524,288

  k_zero<<<130,512,0,stream>>>(attn, 66048);
  k_inorm0<<<64,256,0,stream>>>(x, ng, nb, xa_n);
  k_rfft_row_full<<<dim3(64,8),256,0,stream>>>(xa_n, Cw);
  k_gamma<<<32,256,0,stream>>>(wQ,wQs,bQs, wK,wKs,bKs, gam, gcons);
  k_fft_col_full<<<dim3(64,17),256,0,stream>>>(Cw, F, -1.f);
  k_escore<<<64,256,0,stream>>>(F, Es);
  k_score<<<dim3(2,32,8),256,0,stream>>>(Es, gam, attn);
  k_softmax<<<dim3(2,32),64,0,stream>>>(attn, Es, gcons);
  k_amat<<<2,1024,0,stream>>>(attn, wVs, wPs, Amat);
  k_pmode<<<dim3(2,64,4),256,0,stream>>>(F, attn, wV, wVs, wP, wPs, Pm);
  k_pdhat<<<dim3(2,33,4),256,0,stream>>>(F, Amat, Pm, wP, wPs, bPs, bVs, Pd);
  k_fft_col_full<<<dim3(64,17),256,0,stream>>>(Pd, Ag, 1.f);
  k_irfft_row_addx<<<dim3(64,8),256,0,stream>>>(Ag, x, z, statsZ);
  k_rfft_row_an<<<dim3(64,8),256,0,stream>>>(z, statsZ, ng, nb, Tm);
  k_mfft_col<<<dim3(64,8),256,0,stream>>>(Tm, wM0, Gf);
  k_mifft_col<<<dim3(64,8),256,0,stream>>>(Gf, Am);
  k_mirfft_row<<<dim3(64,8),256,0,stream>>>(Am, fx, stats0);
  k_m0_rfft_row<<<dim3(64,8),256,0,stream>>>(fx, z, stats0, statsZ, ng, nb, wM0s, bM0s, m0b, Tm);
  k_mfft_col<<<dim3(64,8),256,0,stream>>>(Tm, wM1, Gf);
  k_mifft_col<<<dim3(64,8),256,0,stream>>>(Gf, Am);
  k_mirfft_row<<<dim3(64,8),256,0,stream>>>(Am, fx, stats1);
  k_m1_mix<<<dim3(64,8),256,0,stream>>>(fx, m0b, stats1, ng, nb, wM1s, bM1s, fx, stats2);
  k_final<<<dim3(64,8),256,0,stream>>>(fx, z, stats2, statsZ, ng, nb, out);
}